// Round 18
// baseline (126.271 us; speedup 1.0000x reference)
//
#include <hip/hip_runtime.h>
#include <hip/hip_bf16.h>

// ---------------- types ----------------
typedef __bf16 bf16;
typedef __attribute__((ext_vector_type(2))) __bf16 bf16x2;
typedef __attribute__((ext_vector_type(4))) __bf16 bf16x4;
typedef __attribute__((ext_vector_type(8))) __bf16 bf16x8;
typedef __attribute__((ext_vector_type(4))) float f32x4;
typedef __attribute__((ext_vector_type(16))) float f32x16;
typedef unsigned int u32;
typedef __attribute__((ext_vector_type(4))) u32 u32x4;
typedef const __attribute__((address_space(1))) u32* gptr_t;
typedef __attribute__((address_space(3))) u32* lptr_t;

#define N_EMB 1024
#define N_HEAD 16
#define HEAD_DIM 64
#define T_SEQ 2048
#define BATCH 2
#define M_TOT (BATCH * T_SEQ)   // 4096
#define N_QKV (3 * N_EMB)       // 3072
#define KDIM 1024
// scale * log2(e), folded into Q at the QKV epilogue
#define CS_LOG2E 0.1803368801111129f

// round-to-nearest-even f32 -> bf16
__device__ inline unsigned short f2bu(float f) {
    unsigned u = __builtin_bit_cast(unsigned, f);
    return (unsigned short)((u + 0x7fffu + ((u >> 16) & 1u)) >> 16);
}
__device__ inline bf16 f2b(float f) {
    unsigned short s = f2bu(f);
    return __builtin_bit_cast(bf16, s);
}
__device__ inline u32 pkbf(float lo, float hi) {
    bf16x2 t; t[0] = (bf16)lo; t[1] = (bf16)hi;
    return __builtin_bit_cast(u32, t);
}
__device__ __forceinline__ float xhalf_sum(float x) {
    return x + __shfl_xor(x, 32, 64);
}
// full LDS drain + scheduler fence (rule #18): use between LDS producers
// and async LDS writers that vmcnt alone does not order.
__device__ __forceinline__ void lds_fence() {
    asm volatile("s_waitcnt lgkmcnt(0)" ::: "memory");
    __builtin_amdgcn_sched_barrier(0);
}

// ---------------- cast x (f32 -> bf16) ----------------
__global__ __launch_bounds__(256) void k_cast(const float* __restrict__ x,
                                              bf16* __restrict__ xb, int n4) {
    int i = blockIdx.x * 256 + threadIdx.x;
    if (i < n4) {
        float4 v = reinterpret_cast<const float4*>(x)[i];
        ushort4 u;
        u.x = f2bu(v.x); u.y = f2bu(v.y); u.z = f2bu(v.z); u.w = f2bu(v.w);
        reinterpret_cast<ushort4*>(xb)[i] = u;
    }
}

// ---------------- transpose + cast: W [K][N] f32 -> Wt [N][K] bf16 ----------------
__global__ __launch_bounds__(256) void k_transpose(const float* __restrict__ W,
                                                   bf16* __restrict__ Wt,
                                                   int K, int N) {
    __shared__ float tile[32][33];
    int k0 = blockIdx.x * 32;
    int n0 = blockIdx.y * 32;
    int tx = threadIdx.x & 31;
    int ty = threadIdx.x >> 5;
    for (int j = 0; j < 32; j += 8)
        tile[ty + j][tx] = W[(k0 + ty + j) * N + n0 + tx];
    __syncthreads();
    for (int j = 0; j < 32; j += 8)
        Wt[(n0 + ty + j) * (long)K + k0 + tx] = f2b(tile[tx][ty + j]);
}

// ---------------- V transpose+k-permute: [B,H,T,64] -> [B,H,64,T'] ----------------
// V'^T[d][t] = V[pi(t)][d]; pi swaps 4-blocks [4,8)<->[8,12) within each
// 16-group of t, matching the PV B-fragment k-order to P's MFMA C-layout
// (pv_group is shuffle-free).
__global__ __launch_bounds__(256) void k_vtrans(const bf16* __restrict__ v,
                                                bf16* __restrict__ vt) {
    __shared__ bf16 tile[64 * 76];
    const int bh = blockIdx.y;
    const int t0 = blockIdx.x * 64;
    const bf16* src = v + (size_t)bh * T_SEQ * HEAD_DIM;
    bf16* dst = vt + (size_t)bh * HEAD_DIM * T_SEQ;
    const int tid = threadIdx.x;
    #pragma unroll
    for (int it = 0; it < 2; ++it) {
        const int row = (tid >> 3) + it * 32;
        const int col = (tid & 7) * 8;
        bf16x8 val = *reinterpret_cast<const bf16x8*>(src + (size_t)(t0 + row) * HEAD_DIM + col);
        bf16x4 lo;  lo[0] = val[0]; lo[1] = val[1]; lo[2] = val[2]; lo[3] = val[3];
        bf16x4 hiv; hiv[0] = val[4]; hiv[1] = val[5]; hiv[2] = val[6]; hiv[3] = val[7];
        *reinterpret_cast<bf16x4*>(&tile[row * 76 + col]) = lo;
        *reinterpret_cast<bf16x4*>(&tile[row * 76 + col + 4]) = hiv;
    }
    __syncthreads();
    #pragma unroll
    for (int it = 0; it < 2; ++it) {
        const int d  = (tid >> 3) + it * 32;
        const int tt = (tid & 7) * 8;
        bf16x8 val;
        #pragma unroll
        for (int q = 0; q < 8; ++q) {
            const int pq = tt + q;
            const int sw = ((pq >> 2) ^ (pq >> 3)) & 1;
            const int ps = sw ? (pq ^ 12) : pq;
            val[q] = tile[ps * 76 + d];
        }
        *reinterpret_cast<bf16x8*>(dst + (size_t)d * T_SEQ + t0 + tt) = val;
    }
}

// =====================================================================
// 128x128 GEMM main loop (m97 structure) — used by QKV
// =====================================================================
#define GEMM_MAINLOOP(A_, Bt_, m0_, n0_)                                          \
    __shared__ __align__(16) bf16 As[128 * 32];                                   \
    __shared__ __align__(16) bf16 Bs[128 * 32];                                   \
    const int lane = threadIdx.x & 63;                                            \
    const int w    = threadIdx.x >> 6;                                            \
    const int wr   = w >> 1;                                                      \
    const int wc   = w & 1;                                                       \
    const int r    = lane & 15;                                                   \
    const int ko   = (lane >> 4) * 8;                                             \
    const int srow = w * 32 + (lane >> 2);                                        \
    const int sk   = (lane & 3) * 8;                                              \
    const bf16* a_g0 = A_ + (size_t)(m0_ + srow) * KDIM + sk;                     \
    const bf16* a_g1 = a_g0 + 16 * KDIM;                                          \
    const bf16* b_g0 = Bt_ + (size_t)(n0_ + srow) * KDIM + sk;                    \
    const bf16* b_g1 = b_g0 + 16 * KDIM;                                          \
    bf16* a_l0 = As + (w * 2) * 512;                                              \
    bf16* a_l1 = As + (w * 2 + 1) * 512;                                          \
    bf16* b_l0 = Bs + (w * 2) * 512;                                              \
    bf16* b_l1 = Bs + (w * 2 + 1) * 512;                                          \
    f32x4 acc[4][4];                                                              \
    for (int i = 0; i < 4; ++i)                                                   \
        for (int j = 0; j < 4; ++j) acc[i][j] = (f32x4){0.f, 0.f, 0.f, 0.f};      \
    for (int k0 = 0; k0 < KDIM; k0 += 32) {                                       \
        __builtin_amdgcn_global_load_lds((gptr_t)(const void*)(a_g0 + k0),        \
                                         (lptr_t)(void*)a_l0, 16, 0, 0);          \
        __builtin_amdgcn_global_load_lds((gptr_t)(const void*)(a_g1 + k0),        \
                                         (lptr_t)(void*)a_l1, 16, 0, 0);          \
        __builtin_amdgcn_global_load_lds((gptr_t)(const void*)(b_g0 + k0),        \
                                         (lptr_t)(void*)b_l0, 16, 0, 0);          \
        __builtin_amdgcn_global_load_lds((gptr_t)(const void*)(b_g1 + k0),        \
                                         (lptr_t)(void*)b_l1, 16, 0, 0);          \
        __syncthreads();                                                          \
        bf16x8 af[4], bfr[4];                                                     \
        for (int m = 0; m < 4; ++m)                                               \
            af[m] = *reinterpret_cast<const bf16x8*>(As + (wr * 64 + m * 16 + r) * 32 + ko); \
        for (int n = 0; n < 4; ++n)                                               \
            bfr[n] = *reinterpret_cast<const bf16x8*>(Bs + (wc * 64 + n * 16 + r) * 32 + ko); \
        for (int m = 0; m < 4; ++m)                                               \
            for (int n = 0; n < 4; ++n)                                           \
                acc[m][n] = __builtin_amdgcn_mfma_f32_16x16x32_bf16(af[m], bfr[n], acc[m][n], 0, 0, 0); \
        __syncthreads();                                                          \
    }

// =====================================================================
// 64x128 GEMM main loop — used by proj
// =====================================================================
#define GEMM_MAINLOOP_64(A_, Bt_, m0_, n0_)                                       \
    __shared__ __align__(16) bf16 As[64 * 32];                                    \
    __shared__ __align__(16) bf16 Bs[128 * 32];                                   \
    const int lane = threadIdx.x & 63;                                            \
    const int w    = threadIdx.x >> 6;                                            \
    const int wr   = w >> 1;                                                      \
    const int wc   = w & 1;                                                       \
    const int r    = lane & 15;                                                   \
    const int ko   = (lane >> 4) * 8;                                             \
    const int srow = w * 16 + (lane >> 2);                                        \
    const int sk   = (lane & 3) * 8;                                              \
    const bf16* a_g0 = A_ + (size_t)(m0_ + srow) * KDIM + sk;                     \
    const bf16* b_g0 = Bt_ + (size_t)(n0_ + srow) * KDIM + sk;                    \
    const bf16* b_g1 = b_g0 + 64 * KDIM;                                          \
    bf16* a_l0 = As + w * 512;                                                    \
    bf16* b_l0 = Bs + w * 512;                                                    \
    bf16* b_l1 = Bs + 64 * 32 + w * 512;                                          \
    f32x4 acc[2][4];                                                              \
    for (int i = 0; i < 2; ++i)                                                   \
        for (int j = 0; j < 4; ++j) acc[i][j] = (f32x4){0.f, 0.f, 0.f, 0.f};      \
    for (int k0 = 0; k0 < KDIM; k0 += 32) {                                       \
        __builtin_amdgcn_global_load_lds((gptr_t)(const void*)(a_g0 + k0),        \
                                         (lptr_t)(void*)a_l0, 16, 0, 0);          \
        __builtin_amdgcn_global_load_lds((gptr_t)(const void*)(b_g0 + k0),        \
                                         (lptr_t)(void*)b_l0, 16, 0, 0);          \
        __builtin_amdgcn_global_load_lds((gptr_t)(const void*)(b_g1 + k0),        \
                                         (lptr_t)(void*)b_l1, 16, 0, 0);          \
        __syncthreads();                                                          \
        bf16x8 af[2], bfr[4];                                                     \
        for (int m = 0; m < 2; ++m)                                               \
            af[m] = *reinterpret_cast<const bf16x8*>(As + (wr * 32 + m * 16 + r) * 32 + ko); \
        for (int n = 0; n < 4; ++n)                                               \
            bfr[n] = *reinterpret_cast<const bf16x8*>(Bs + (wc * 64 + n * 16 + r) * 32 + ko); \
        for (int m = 0; m < 2; ++m)                                               \
            for (int n = 0; n < 4; ++n)                                           \
                acc[m][n] = __builtin_amdgcn_mfma_f32_16x16x32_bf16(af[m], bfr[n], acc[m][n], 0, 0, 0); \
        __syncthreads();                                                          \
    }

// ---------------- QKV GEMM -> q/k/v [B,H,T,64] bf16 (q pre-scaled by CS_LOG2E) ----------------
__global__ __launch_bounds__(256) void k_gemm_qkv(const bf16* __restrict__ A,
                                                  const bf16* __restrict__ Bt,
                                                  const float* __restrict__ bias,
                                                  bf16* __restrict__ qb,
                                                  bf16* __restrict__ kb,
                                                  bf16* __restrict__ vb) {
    const int m0 = blockIdx.x * 128;
    const int n0 = blockIdx.y * 128;
    GEMM_MAINLOOP(A, Bt, m0, n0)
    const int col   = lane & 15;
    const int rbase = (lane >> 4) * 4;
    for (int nn = 0; nn < 4; ++nn) {
        int n = n0 + wc * 64 + nn * 16 + col;
        float bv = bias[n];
        int which = n >> 10;
        int c  = n & 1023;
        int h  = c >> 6;
        int dh = c & 63;
        bf16* dst = (which == 0) ? qb : ((which == 1) ? kb : vb);
        const float sc = (which == 0) ? CS_LOG2E : 1.0f;
        for (int mm = 0; mm < 4; ++mm) {
            for (int i = 0; i < 4; ++i) {
                int m = m0 + wr * 64 + mm * 16 + rbase + i;
                int b_ = m >> 11;
                int t  = m & 2047;
                dst[(((b_ * N_HEAD + h) * T_SEQ) + t) * HEAD_DIM + dh] =
                    f2b((acc[mm][nn][i] + bv) * sc);
            }
        }
    }
}

// ---------------- proj GEMM (64x128 tiles) ----------------
__global__ __launch_bounds__(256) void k_gemm_proj(const bf16* __restrict__ A,
                                                   const bf16* __restrict__ Bt,
                                                   const float* __restrict__ bias,
                                                   float* __restrict__ out) {
    const int m0 = blockIdx.x * 64;
    const int n0 = blockIdx.y * 128;
    GEMM_MAINLOOP_64(A, Bt, m0, n0)
    const int col   = lane & 15;
    const int rbase = (lane >> 4) * 4;
    for (int nn = 0; nn < 4; ++nn) {
        int n = n0 + wc * 64 + nn * 16 + col;
        float bv = bias[n];
        for (int mm = 0; mm < 2; ++mm) {
            for (int i = 0; i < 4; ++i) {
                int m = m0 + wr * 32 + mm * 16 + rbase + i;
                out[(size_t)m * N_EMB + n] = acc[mm][nn][i] + bv;
            }
        }
    }
}

// =====================================================================
// flash attention helpers. Fixed-max softmax (Q pre-scaled, log2 units).
// Per-WAVE private LDS slice + T14 async-STAGE pipeline. RACE FIX (R17):
// ds_reads are NOT ordered against async global_load_lds writes to the
// same addresses (vmcnt only tracks the load; the TA->LDS write can land
// before an outstanding ds_read samples). lds_fence() after fragment
// reads / pipeline writes enforces ordering.
// =====================================================================
__device__ __forceinline__ void pv_group(const float* p,
                                         const bf16x8 (&va)[2][2], f32x16 (&o)[2]) {
    u32x4 f0, f1;
    f0[0] = pkbf(p[0], p[1]);   f0[1] = pkbf(p[2], p[3]);
    f0[2] = pkbf(p[4], p[5]);   f0[3] = pkbf(p[6], p[7]);
    f1[0] = pkbf(p[8], p[9]);   f1[1] = pkbf(p[10], p[11]);
    f1[2] = pkbf(p[12], p[13]); f1[3] = pkbf(p[14], p[15]);
    bf16x8 pb0 = __builtin_bit_cast(bf16x8, f0);
    bf16x8 pb1 = __builtin_bit_cast(bf16x8, f1);
    __builtin_amdgcn_s_setprio(1);
    #pragma unroll
    for (int dt = 0; dt < 2; ++dt) {
        o[dt] = __builtin_amdgcn_mfma_f32_32x32x16_bf16(va[dt][0], pb0, o[dt], 0, 0, 0);
        o[dt] = __builtin_amdgcn_mfma_f32_32x32x16_bf16(va[dt][1], pb1, o[dt], 0, 0, 0);
    }
    __builtin_amdgcn_s_setprio(0);
}

// initial staging via global_load_lds (prologue only)
__device__ __forceinline__ void stage_k32(const char* Kg, char* Ks, int kbase, int lane) {
    #pragma unroll
    for (int rr = 0; rr < 4; ++rr) {
        const int fb  = rr * 1024 + lane * 16;
        const int row = fb >> 7;
        const int swz = (row & 7) << 4;
        __builtin_amdgcn_global_load_lds(
            (gptr_t)(const void*)(Kg + (size_t)kbase * 128 + (fb ^ swz)),
            (lptr_t)(void*)(Ks + rr * 1024), 16, 0, 0);
    }
}
__device__ __forceinline__ void stage_v32(const char* Vg, char* Vs, int kbase, int lane) {
    #pragma unroll
    for (int rr = 0; rr < 4; ++rr) {
        const int fb  = rr * 1024 + lane * 16;
        const int d   = fb >> 6;
        const int off = fb & 63;
        const int swz = (d & 3) << 4;
        __builtin_amdgcn_global_load_lds(
            (gptr_t)(const void*)(Vg + (size_t)d * (T_SEQ * 2) + (size_t)kbase * 2 + (off ^ swz)),
            (lptr_t)(void*)(Vs + rr * 1024), 16, 0, 0);
    }
}

// T14 register prefetch (same source addressing as stage_*, dest = VGPRs)
__device__ __forceinline__ void prefetch_k32(const char* Kg, int kbase, int lane,
                                             bf16x8 (&kr)[4]) {
    #pragma unroll
    for (int rr = 0; rr < 4; ++rr) {
        const int fb  = rr * 1024 + lane * 16;
        const int row = fb >> 7;
        const int swz = (row & 7) << 4;
        kr[rr] = *reinterpret_cast<const bf16x8*>(
            Kg + (size_t)kbase * 128 + (fb ^ swz));
    }
}
__device__ __forceinline__ void prefetch_v32(const char* Vg, int kbase, int lane,
                                             bf16x8 (&vr)[4]) {
    #pragma unroll
    for (int rr = 0; rr < 4; ++rr) {
        const int fb  = rr * 1024 + lane * 16;
        const int d   = fb >> 6;
        const int off = fb & 63;
        const int swz = (d & 3) << 4;
        vr[rr] = *reinterpret_cast<const bf16x8*>(
            Vg + (size_t)d * (T_SEQ * 2) + (size_t)kbase * 2 + (off ^ swz));
    }
}
__device__ __forceinline__ void write_kv(char* Ks, char* Vs, int lane,
                                         const bf16x8 (&kr)[4], const bf16x8 (&vr)[4]) {
    #pragma unroll
    for (int rr = 0; rr < 4; ++rr) {
        *reinterpret_cast<bf16x8*>(Ks + rr * 1024 + lane * 16) = kr[rr];
        *reinterpret_cast<bf16x8*>(Vs + rr * 1024 + lane * 16) = vr[rr];
    }
}

// compute one 32-k tile from the wave's private LDS slice
__device__ __forceinline__ void tile32_w(const char* Ks, const char* Vs,
                                         int qr, int hi, const bf16x8 (&qf)[4],
                                         bool diag, float& l_r, f32x16 (&o)[2]) {
    const int swzk = (qr & 7) << 4;
    bf16x8 kf[4];
    #pragma unroll
    for (int f = 0; f < 4; ++f)
        kf[f] = *reinterpret_cast<const bf16x8*>(
            Ks + ((qr * 128 + f * 32 + hi * 16) ^ swzk));
    f32x16 st;
    #pragma unroll
    for (int r = 0; r < 16; ++r) st[r] = 0.f;
    __builtin_amdgcn_s_setprio(1);
    #pragma unroll
    for (int f = 0; f < 4; ++f)
        st = __builtin_amdgcn_mfma_f32_32x32x16_bf16(kf[f], qf[f], st, 0, 0, 0);
    __builtin_amdgcn_s_setprio(0);
    if (diag) {
        const int kp4 = 4 * hi;
        #pragma unroll
        for (int r = 0; r < 16; ++r) {
            const int kpos = (r & 3) + 8 * (r >> 2) + kp4;
            if (kpos > qr) st[r] = -3.0e38f;
        }
    }
    bf16x8 va[2][2];
    #pragma unroll
    for (int dt = 0; dt < 2; ++dt)
        #pragma unroll
        for (int ks = 0; ks < 2; ++ks) {
            const int d = dt * 32 + qr;
            va[dt][ks] = *reinterpret_cast<const bf16x8*>(
                Vs + ((d * 64 + ks * 32 + hi * 16) ^ ((d & 3) << 4)));
        }
    float p[16];
    #pragma unroll
    for (int r = 0; r < 16; ++r) p[r] = exp2f(st[r]);   // masked -3e38 underflows to 0
    float s = 0.f;
    #pragma unroll
    for (int r = 0; r < 8; ++r) s += p[r] + p[r + 8];
    l_r += s;
    pv_group(p, va, o);
}

// =====================================================================
// flash attention: block = (bh, qblk), 4 waves, 4-way split-K. Each wave
// has a PRIVATE 8KB LDS slice; T14 pipeline (reg-prefetch t+1, compute t,
// ds_write t+1 + fence) — no barriers in the loop. 2048 blocks,
// heavy-first, XCD-pinned bh. Combine via LDS slab reuse.
// =====================================================================
__global__ __launch_bounds__(256) void k_attn(const bf16* __restrict__ qb,
                                              const bf16* __restrict__ kb,
                                              const bf16* __restrict__ vtb,
                                              bf16* __restrict__ yb) {
    const int lane = threadIdx.x & 63;
    const int wv   = threadIdx.x >> 6;   // 0..3
    const int bh   = blockIdx.x;         // 0..31  (XCD = bh % 8)
    const int qblk = 63 - blockIdx.y;    // heavy-first
    const int q0   = qblk * 32;
    const int b    = bh >> 4;
    const int h    = bh & 15;

    const char* Qg = (const char*)(qb  + (size_t)bh * T_SEQ * HEAD_DIM);
    const char* Kg = (const char*)(kb  + (size_t)bh * T_SEQ * HEAD_DIM);
    const char* Vg = (const char*)(vtb + (size_t)bh * HEAD_DIM * T_SEQ);

    const int qr = lane & 31;
    const int hi = lane >> 5;

    __shared__ __align__(16) char sbuf[4][8192];   // per-wave private slice
    __shared__ float ls_l[3][64];
    char* Ks = sbuf[wv];
    char* Vs = sbuf[wv] + 4096;

    // ---- Q fragments: stage via own slice (coalesced), then read ----
    stage_k32(Qg, Ks, qblk * 32, lane);   // Q rows q0..q0+31, same layout as K
    asm volatile("s_waitcnt vmcnt(0)" ::: "memory");
    bf16x8 qf[4];
    {
        const int swzk = (qr & 7) << 4;
        #pragma unroll
        for (int f = 0; f < 4; ++f)
            qf[f] = *reinterpret_cast<const bf16x8*>(
                Ks + ((qr * 128 + f * 32 + hi * 16) ^ swzk));
    }
    // RACE FIX: drain the qf ds_reads BEFORE K staging overwrites this LDS.
    lds_fence();

    f32x16 o[2];
    #pragma unroll
    for (int r = 0; r < 16; ++r) { o[0][r] = 0.f; o[1][r] = 0.f; }
    float l_r = 0.f;

    // 4-way split-K: wave wv owns a contiguous chunk; last chunk has diag.
    const int n    = qblk + 1;
    const int base = n >> 2;
    const int rem  = n & 3;
    const int lo   = wv * base + (wv < rem ? wv : rem);
    const int cnt  = base + (wv < rem ? 1 : 0);
    const int end  = lo + cnt;

    if (cnt > 0) {
        // prologue: stage first tile into LDS
        stage_k32(Kg, Ks, lo * 32, lane);
        stage_v32(Vg, Vs, lo * 32, lane);
        asm volatile("s_waitcnt vmcnt(0)" ::: "memory");
        for (int t = lo; t < end; ++t) {
            bf16x8 kr[4], vr[4];
            const bool pf = (t + 1 < end);
            if (pf) {                                 // issue t+1 loads -> regs
                prefetch_k32(Kg, (t + 1) * 32, lane, kr);
                prefetch_v32(Vg, (t + 1) * 32, lane, vr);
            }
            tile32_w(Ks, Vs, qr, hi, qf, t == qblk, l_r, o);   // compute t
            if (pf) {
                write_kv(Ks, Vs, lane, kr, vr);      // land t+1
                lds_fence();                         // writes visible before next reads
            }
        }
    }

    // ---- combine across 4 waves: o -> own slab (i-major), plain sums ----
    float* slab = (float*)sbuf[wv];   // 2048 f32 = 64 lanes x 32 exactly
    if (wv > 0) {
        #pragma unroll
        for (int i = 0; i < 16; ++i) {
            slab[i * 64 + lane]        = o[0][i];
            slab[(16 + i) * 64 + lane] = o[1][i];
        }
        ls_l[wv - 1][lane] = l_r;
    }
    __syncthreads();
    if (wv > 0) return;
    #pragma unroll
    for (int s = 1; s < 4; ++s) {
        const float* sl = (const float*)sbuf[s];
        l_r += ls_l[s - 1][lane];
        #pragma unroll
        for (int i = 0; i < 16; ++i) {
            o[0][i] += sl[i * 64 + lane];
            o[1][i] += sl[(16 + i) * 64 + lane];
        }
    }
    l_r = xhalf_sum(l_r);

    // ---- epilogue: O^T[d][q] / l -> y[b][t][h*64+d] ----
    const float inv = 1.f / fmaxf(l_r, 1e-30f);
    const int tq = q0 + qr;
    bf16* yrow = yb + ((size_t)(b * T_SEQ + tq)) * N_EMB + h * HEAD_DIM;
    #pragma unroll
    for (int dt = 0; dt < 2; ++dt) {
        #pragma unroll
        for (int rr = 0; rr < 4; ++rr) {
            const int d0 = dt * 32 + 8 * rr + 4 * hi;
            ushort4 u;
            u.x = f2bu(o[dt][4 * rr + 0] * inv);
            u.y = f2bu(o[dt][4 * rr + 1] * inv);
            u.z = f2bu(o[dt][4 * rr + 2] * inv);
            u.w = f2bu(o[dt][4 * rr + 3] * inv);
            *reinterpret_cast<ushort4*>(yrow + d0) = u;
        }
    }
}

extern "C" void kernel_launch(void* const* d_in, const int* in_sizes, int n_in,
                              void* d_out, int out_size, void* d_ws, size_t ws_size,
                              hipStream_t stream) {
    const float* x      = (const float*)d_in[0];
    const float* W_attn = (const float*)d_in[1];
    const float* b_attn = (const float*)d_in[2];
    const float* W_proj = (const float*)d_in[3];
    const float* b_proj = (const float*)d_in[4];
    float* out = (float*)d_out;

    const size_t sz_x   = (size_t)M_TOT * N_EMB;
    const size_t sz_wat = (size_t)N_QKV * N_EMB;
    const size_t sz_wpt = (size_t)N_EMB * N_EMB;
    const size_t sz_hd  = (size_t)BATCH * N_HEAD * T_SEQ * HEAD_DIM;
    const size_t need = (sz_x + sz_wat + sz_wpt + 3 * sz_hd + sz_x) * sizeof(bf16);
    if (ws_size < need) return;

    bf16* xb  = (bf16*)d_ws;       // dead after QKV GEMM -> reused for V^T
    bf16* wat = xb + sz_x;
    bf16* wpt = wat + sz_wat;
    bf16* qb  = wpt + sz_wpt;
    bf16* kbf = qb + sz_hd;
    bf16* vbf = kbf + sz_hd;
    bf16* yb  = vbf + sz_hd;
    bf16* vtb = xb;                // V^T [B,H,64,T] (k-permuted)

    k_cast<<<dim3((sz_x / 4 + 255) / 256), 256, 0, stream>>>(x, xb, (int)(sz_x / 4));
    k_transpose<<<dim3(N_EMB / 32, N_QKV / 32), 256, 0, stream>>>(W_attn, wat, N_EMB, N_QKV);
    k_transpose<<<dim3(N_EMB / 32, N_EMB / 32), 256, 0, stream>>>(W_proj, wpt, N_EMB, N_EMB);
    k_gemm_qkv<<<dim3(M_TOT / 128, N_QKV / 128), 256, 0, stream>>>(xb, wat, b_attn, qb, kbf, vbf);
    k_vtrans<<<dim3(T_SEQ / 64, BATCH * N_HEAD), 256, 0, stream>>>(vbf, vtb);
    k_attn<<<dim3(BATCH * N_HEAD, 64), 256, 0, stream>>>(qb, kbf, vtb, yb);
    k_gemm_proj<<<dim3(M_TOT / 64, N_EMB / 128), 256, 0, stream>>>(yb, wpt, b_proj, out);
}

// Round 19
// 116.329 us; speedup vs baseline: 1.0855x; 1.0855x over previous
//
#include <hip/hip_runtime.h>
#include <hip/hip_bf16.h>

// ---------------- types ----------------
typedef __bf16 bf16;
typedef __attribute__((ext_vector_type(2))) __bf16 bf16x2;
typedef __attribute__((ext_vector_type(4))) __bf16 bf16x4;
typedef __attribute__((ext_vector_type(8))) __bf16 bf16x8;
typedef __attribute__((ext_vector_type(4))) float f32x4;
typedef __attribute__((ext_vector_type(16))) float f32x16;
typedef unsigned int u32;
typedef __attribute__((ext_vector_type(4))) u32 u32x4;
typedef const __attribute__((address_space(1))) u32* gptr_t;
typedef __attribute__((address_space(3))) u32* lptr_t;

#define N_EMB 1024
#define N_HEAD 16
#define HEAD_DIM 64
#define T_SEQ 2048
#define BATCH 2
#define M_TOT (BATCH * T_SEQ)   // 4096
#define N_QKV (3 * N_EMB)       // 3072
#define KDIM 1024
// scale * log2(e), folded into Q at the QKV epilogue
#define CS_LOG2E 0.1803368801111129f

// round-to-nearest-even f32 -> bf16
__device__ inline unsigned short f2bu(float f) {
    unsigned u = __builtin_bit_cast(unsigned, f);
    return (unsigned short)((u + 0x7fffu + ((u >> 16) & 1u)) >> 16);
}
__device__ inline bf16 f2b(float f) {
    unsigned short s = f2bu(f);
    return __builtin_bit_cast(bf16, s);
}
__device__ inline u32 pkbf(float lo, float hi) {
    bf16x2 t; t[0] = (bf16)lo; t[1] = (bf16)hi;
    return __builtin_bit_cast(u32, t);
}
__device__ __forceinline__ float xhalf_sum(float x) {
    return x + __shfl_xor(x, 32, 64);
}
// full LDS drain + scheduler fence (rule #18): used ONCE after qf reads,
// before async staging can overwrite the same LDS.
__device__ __forceinline__ void lds_fence() {
    asm volatile("s_waitcnt lgkmcnt(0)" ::: "memory");
    __builtin_amdgcn_sched_barrier(0);
}
// bare drain (no scheduler pin): guarantees outstanding ds_reads complete
// before the next tile's async LDS writes can land. Nearly free when
// compute already consumed all reads.
__device__ __forceinline__ void lds_drain() {
    asm volatile("s_waitcnt lgkmcnt(0)" ::: "memory");
}

// ---------------- cast x (f32 -> bf16) ----------------
__global__ __launch_bounds__(256) void k_cast(const float* __restrict__ x,
                                              bf16* __restrict__ xb, int n4) {
    int i = blockIdx.x * 256 + threadIdx.x;
    if (i < n4) {
        float4 v = reinterpret_cast<const float4*>(x)[i];
        ushort4 u;
        u.x = f2bu(v.x); u.y = f2bu(v.y); u.z = f2bu(v.z); u.w = f2bu(v.w);
        reinterpret_cast<ushort4*>(xb)[i] = u;
    }
}

// ---------------- transpose + cast: W [K][N] f32 -> Wt [N][K] bf16 ----------------
__global__ __launch_bounds__(256) void k_transpose(const float* __restrict__ W,
                                                   bf16* __restrict__ Wt,
                                                   int K, int N) {
    __shared__ float tile[32][33];
    int k0 = blockIdx.x * 32;
    int n0 = blockIdx.y * 32;
    int tx = threadIdx.x & 31;
    int ty = threadIdx.x >> 5;
    for (int j = 0; j < 32; j += 8)
        tile[ty + j][tx] = W[(k0 + ty + j) * N + n0 + tx];
    __syncthreads();
    for (int j = 0; j < 32; j += 8)
        Wt[(n0 + ty + j) * (long)K + k0 + tx] = f2b(tile[tx][ty + j]);
}

// ---------------- V transpose+k-permute: [B,H,T,64] -> [B,H,64,T'] ----------------
// V'^T[d][t] = V[pi(t)][d]; pi swaps 4-blocks [4,8)<->[8,12) within each
// 16-group of t, matching the PV B-fragment k-order to P's MFMA C-layout
// (pv_group is shuffle-free).
__global__ __launch_bounds__(256) void k_vtrans(const bf16* __restrict__ v,
                                                bf16* __restrict__ vt) {
    __shared__ bf16 tile[64 * 76];
    const int bh = blockIdx.y;
    const int t0 = blockIdx.x * 64;
    const bf16* src = v + (size_t)bh * T_SEQ * HEAD_DIM;
    bf16* dst = vt + (size_t)bh * HEAD_DIM * T_SEQ;
    const int tid = threadIdx.x;
    #pragma unroll
    for (int it = 0; it < 2; ++it) {
        const int row = (tid >> 3) + it * 32;
        const int col = (tid & 7) * 8;
        bf16x8 val = *reinterpret_cast<const bf16x8*>(src + (size_t)(t0 + row) * HEAD_DIM + col);
        bf16x4 lo;  lo[0] = val[0]; lo[1] = val[1]; lo[2] = val[2]; lo[3] = val[3];
        bf16x4 hiv; hiv[0] = val[4]; hiv[1] = val[5]; hiv[2] = val[6]; hiv[3] = val[7];
        *reinterpret_cast<bf16x4*>(&tile[row * 76 + col]) = lo;
        *reinterpret_cast<bf16x4*>(&tile[row * 76 + col + 4]) = hiv;
    }
    __syncthreads();
    #pragma unroll
    for (int it = 0; it < 2; ++it) {
        const int d  = (tid >> 3) + it * 32;
        const int tt = (tid & 7) * 8;
        bf16x8 val;
        #pragma unroll
        for (int q = 0; q < 8; ++q) {
            const int pq = tt + q;
            const int sw = ((pq >> 2) ^ (pq >> 3)) & 1;
            const int ps = sw ? (pq ^ 12) : pq;
            val[q] = tile[ps * 76 + d];
        }
        *reinterpret_cast<bf16x8*>(dst + (size_t)d * T_SEQ + t0 + tt) = val;
    }
}

// =====================================================================
// 128x128 GEMM main loop (m97 structure) — used by QKV
// =====================================================================
#define GEMM_MAINLOOP(A_, Bt_, m0_, n0_)                                          \
    __shared__ __align__(16) bf16 As[128 * 32];                                   \
    __shared__ __align__(16) bf16 Bs[128 * 32];                                   \
    const int lane = threadIdx.x & 63;                                            \
    const int w    = threadIdx.x >> 6;                                            \
    const int wr   = w >> 1;                                                      \
    const int wc   = w & 1;                                                       \
    const int r    = lane & 15;                                                   \
    const int ko   = (lane >> 4) * 8;                                             \
    const int srow = w * 32 + (lane >> 2);                                        \
    const int sk   = (lane & 3) * 8;                                              \
    const bf16* a_g0 = A_ + (size_t)(m0_ + srow) * KDIM + sk;                     \
    const bf16* a_g1 = a_g0 + 16 * KDIM;                                          \
    const bf16* b_g0 = Bt_ + (size_t)(n0_ + srow) * KDIM + sk;                    \
    const bf16* b_g1 = b_g0 + 16 * KDIM;                                          \
    bf16* a_l0 = As + (w * 2) * 512;                                              \
    bf16* a_l1 = As + (w * 2 + 1) * 512;                                          \
    bf16* b_l0 = Bs + (w * 2) * 512;                                              \
    bf16* b_l1 = Bs + (w * 2 + 1) * 512;                                          \
    f32x4 acc[4][4];                                                              \
    for (int i = 0; i < 4; ++i)                                                   \
        for (int j = 0; j < 4; ++j) acc[i][j] = (f32x4){0.f, 0.f, 0.f, 0.f};      \
    for (int k0 = 0; k0 < KDIM; k0 += 32) {                                       \
        __builtin_amdgcn_global_load_lds((gptr_t)(const void*)(a_g0 + k0),        \
                                         (lptr_t)(void*)a_l0, 16, 0, 0);          \
        __builtin_amdgcn_global_load_lds((gptr_t)(const void*)(a_g1 + k0),        \
                                         (lptr_t)(void*)a_l1, 16, 0, 0);          \
        __builtin_amdgcn_global_load_lds((gptr_t)(const void*)(b_g0 + k0),        \
                                         (lptr_t)(void*)b_l0, 16, 0, 0);          \
        __builtin_amdgcn_global_load_lds((gptr_t)(const void*)(b_g1 + k0),        \
                                         (lptr_t)(void*)b_l1, 16, 0, 0);          \
        __syncthreads();                                                          \
        bf16x8 af[4], bfr[4];                                                     \
        for (int m = 0; m < 4; ++m)                                               \
            af[m] = *reinterpret_cast<const bf16x8*>(As + (wr * 64 + m * 16 + r) * 32 + ko); \
        for (int n = 0; n < 4; ++n)                                               \
            bfr[n] = *reinterpret_cast<const bf16x8*>(Bs + (wc * 64 + n * 16 + r) * 32 + ko); \
        for (int m = 0; m < 4; ++m)                                               \
            for (int n = 0; n < 4; ++n)                                           \
                acc[m][n] = __builtin_amdgcn_mfma_f32_16x16x32_bf16(af[m], bfr[n], acc[m][n], 0, 0, 0); \
        __syncthreads();                                                          \
    }

// =====================================================================
// 64x128 GEMM main loop — used by proj
// =====================================================================
#define GEMM_MAINLOOP_64(A_, Bt_, m0_, n0_)                                       \
    __shared__ __align__(16) bf16 As[64 * 32];                                    \
    __shared__ __align__(16) bf16 Bs[128 * 32];                                   \
    const int lane = threadIdx.x & 63;                                            \
    const int w    = threadIdx.x >> 6;                                            \
    const int wr   = w >> 1;                                                      \
    const int wc   = w & 1;                                                       \
    const int r    = lane & 15;                                                   \
    const int ko   = (lane >> 4) * 8;                                             \
    const int srow = w * 16 + (lane >> 2);                                        \
    const int sk   = (lane & 3) * 8;                                              \
    const bf16* a_g0 = A_ + (size_t)(m0_ + srow) * KDIM + sk;                     \
    const bf16* b_g0 = Bt_ + (size_t)(n0_ + srow) * KDIM + sk;                    \
    const bf16* b_g1 = b_g0 + 64 * KDIM;                                          \
    bf16* a_l0 = As + w * 512;                                                    \
    bf16* b_l0 = Bs + w * 512;                                                    \
    bf16* b_l1 = Bs + 64 * 32 + w * 512;                                          \
    f32x4 acc[2][4];                                                              \
    for (int i = 0; i < 2; ++i)                                                   \
        for (int j = 0; j < 4; ++j) acc[i][j] = (f32x4){0.f, 0.f, 0.f, 0.f};      \
    for (int k0 = 0; k0 < KDIM; k0 += 32) {                                       \
        __builtin_amdgcn_global_load_lds((gptr_t)(const void*)(a_g0 + k0),        \
                                         (lptr_t)(void*)a_l0, 16, 0, 0);          \
        __builtin_amdgcn_global_load_lds((gptr_t)(const void*)(b_g0 + k0),        \
                                         (lptr_t)(void*)b_l0, 16, 0, 0);          \
        __builtin_amdgcn_global_load_lds((gptr_t)(const void*)(b_g1 + k0),        \
                                         (lptr_t)(void*)b_l1, 16, 0, 0);          \
        __syncthreads();                                                          \
        bf16x8 af[2], bfr[4];                                                     \
        for (int m = 0; m < 2; ++m)                                               \
            af[m] = *reinterpret_cast<const bf16x8*>(As + (wr * 32 + m * 16 + r) * 32 + ko); \
        for (int n = 0; n < 4; ++n)                                               \
            bfr[n] = *reinterpret_cast<const bf16x8*>(Bs + (wc * 64 + n * 16 + r) * 32 + ko); \
        for (int m = 0; m < 2; ++m)                                               \
            for (int n = 0; n < 4; ++n)                                           \
                acc[m][n] = __builtin_amdgcn_mfma_f32_16x16x32_bf16(af[m], bfr[n], acc[m][n], 0, 0, 0); \
        __syncthreads();                                                          \
    }

// ---------------- QKV GEMM -> q/k/v [B,H,T,64] bf16 (q pre-scaled by CS_LOG2E) ----------------
__global__ __launch_bounds__(256) void k_gemm_qkv(const bf16* __restrict__ A,
                                                  const bf16* __restrict__ Bt,
                                                  const float* __restrict__ bias,
                                                  bf16* __restrict__ qb,
                                                  bf16* __restrict__ kb,
                                                  bf16* __restrict__ vb) {
    const int m0 = blockIdx.x * 128;
    const int n0 = blockIdx.y * 128;
    GEMM_MAINLOOP(A, Bt, m0, n0)
    const int col   = lane & 15;
    const int rbase = (lane >> 4) * 4;
    for (int nn = 0; nn < 4; ++nn) {
        int n = n0 + wc * 64 + nn * 16 + col;
        float bv = bias[n];
        int which = n >> 10;
        int c  = n & 1023;
        int h  = c >> 6;
        int dh = c & 63;
        bf16* dst = (which == 0) ? qb : ((which == 1) ? kb : vb);
        const float sc = (which == 0) ? CS_LOG2E : 1.0f;
        for (int mm = 0; mm < 4; ++mm) {
            for (int i = 0; i < 4; ++i) {
                int m = m0 + wr * 64 + mm * 16 + rbase + i;
                int b_ = m >> 11;
                int t  = m & 2047;
                dst[(((b_ * N_HEAD + h) * T_SEQ) + t) * HEAD_DIM + dh] =
                    f2b((acc[mm][nn][i] + bv) * sc);
            }
        }
    }
}

// ---------------- proj GEMM (64x128 tiles) ----------------
__global__ __launch_bounds__(256) void k_gemm_proj(const bf16* __restrict__ A,
                                                   const bf16* __restrict__ Bt,
                                                   const float* __restrict__ bias,
                                                   float* __restrict__ out) {
    const int m0 = blockIdx.x * 64;
    const int n0 = blockIdx.y * 128;
    GEMM_MAINLOOP_64(A, Bt, m0, n0)
    const int col   = lane & 15;
    const int rbase = (lane >> 4) * 4;
    for (int nn = 0; nn < 4; ++nn) {
        int n = n0 + wc * 64 + nn * 16 + col;
        float bv = bias[n];
        for (int mm = 0; mm < 2; ++mm) {
            for (int i = 0; i < 4; ++i) {
                int m = m0 + wr * 32 + mm * 16 + rbase + i;
                out[(size_t)m * N_EMB + n] = acc[mm][nn][i] + bv;
            }
        }
    }
}

// =====================================================================
// flash attention helpers. Fixed-max softmax (Q pre-scaled, log2 units).
// R16 staging structure (global_load_lds + vmcnt(0) per tile — faster
// than R18's reg-prefetch pipeline: lower VGPR, no sched_barrier pin)
// + the R18 correctness fences (qf lds_fence once; bare lgkmcnt drain
// before each staging so ds_reads never race the async LDS writes).
// V is k-permuted (k_vtrans) so pv_group is shuffle-free.
// =====================================================================
__device__ __forceinline__ void pv_group(const float* p,
                                         const bf16x8 (&va)[2][2], f32x16 (&o)[2]) {
    u32x4 f0, f1;
    f0[0] = pkbf(p[0], p[1]);   f0[1] = pkbf(p[2], p[3]);
    f0[2] = pkbf(p[4], p[5]);   f0[3] = pkbf(p[6], p[7]);
    f1[0] = pkbf(p[8], p[9]);   f1[1] = pkbf(p[10], p[11]);
    f1[2] = pkbf(p[12], p[13]); f1[3] = pkbf(p[14], p[15]);
    bf16x8 pb0 = __builtin_bit_cast(bf16x8, f0);
    bf16x8 pb1 = __builtin_bit_cast(bf16x8, f1);
    __builtin_amdgcn_s_setprio(1);
    #pragma unroll
    for (int dt = 0; dt < 2; ++dt) {
        o[dt] = __builtin_amdgcn_mfma_f32_32x32x16_bf16(va[dt][0], pb0, o[dt], 0, 0, 0);
        o[dt] = __builtin_amdgcn_mfma_f32_32x32x16_bf16(va[dt][1], pb1, o[dt], 0, 0, 0);
    }
    __builtin_amdgcn_s_setprio(0);
}

// stage one 32-k tile: K 32 rows x 128B (swz (row&7)<<4), V 64 d-rows x 64B
// (swz (d&3)<<4). 4 x 1KB coalesced global_load_lds each.
__device__ __forceinline__ void stage_k32(const char* Kg, char* Ks, int kbase, int lane) {
    #pragma unroll
    for (int rr = 0; rr < 4; ++rr) {
        const int fb  = rr * 1024 + lane * 16;
        const int row = fb >> 7;
        const int swz = (row & 7) << 4;
        __builtin_amdgcn_global_load_lds(
            (gptr_t)(const void*)(Kg + (size_t)kbase * 128 + (fb ^ swz)),
            (lptr_t)(void*)(Ks + rr * 1024), 16, 0, 0);
    }
}
__device__ __forceinline__ void stage_v32(const char* Vg, char* Vs, int kbase, int lane) {
    #pragma unroll
    for (int rr = 0; rr < 4; ++rr) {
        const int fb  = rr * 1024 + lane * 16;
        const int d   = fb >> 6;
        const int off = fb & 63;
        const int swz = (d & 3) << 4;
        __builtin_amdgcn_global_load_lds(
            (gptr_t)(const void*)(Vg + (size_t)d * (T_SEQ * 2) + (size_t)kbase * 2 + (off ^ swz)),
            (lptr_t)(void*)(Vs + rr * 1024), 16, 0, 0);
    }
}

// compute one 32-k tile from the wave's private LDS slice
__device__ __forceinline__ void tile32_w(const char* Ks, const char* Vs,
                                         int qr, int hi, const bf16x8 (&qf)[4],
                                         bool diag, float& l_r, f32x16 (&o)[2]) {
    const int swzk = (qr & 7) << 4;
    bf16x8 kf[4];
    #pragma unroll
    for (int f = 0; f < 4; ++f)
        kf[f] = *reinterpret_cast<const bf16x8*>(
            Ks + ((qr * 128 + f * 32 + hi * 16) ^ swzk));
    f32x16 st;
    #pragma unroll
    for (int r = 0; r < 16; ++r) st[r] = 0.f;
    __builtin_amdgcn_s_setprio(1);
    #pragma unroll
    for (int f = 0; f < 4; ++f)
        st = __builtin_amdgcn_mfma_f32_32x32x16_bf16(kf[f], qf[f], st, 0, 0, 0);
    __builtin_amdgcn_s_setprio(0);
    if (diag) {
        const int kp4 = 4 * hi;
        #pragma unroll
        for (int r = 0; r < 16; ++r) {
            const int kpos = (r & 3) + 8 * (r >> 2) + kp4;
            if (kpos > qr) st[r] = -3.0e38f;
        }
    }
    bf16x8 va[2][2];
    #pragma unroll
    for (int dt = 0; dt < 2; ++dt)
        #pragma unroll
        for (int ks = 0; ks < 2; ++ks) {
            const int d = dt * 32 + qr;
            va[dt][ks] = *reinterpret_cast<const bf16x8*>(
                Vs + ((d * 64 + ks * 32 + hi * 16) ^ ((d & 3) << 4)));
        }
    float p[16];
    #pragma unroll
    for (int r = 0; r < 16; ++r) p[r] = exp2f(st[r]);   // masked -3e38 underflows to 0
    float s = 0.f;
    #pragma unroll
    for (int r = 0; r < 8; ++r) s += p[r] + p[r + 8];
    l_r += s;
    pv_group(p, va, o);
}

// =====================================================================
// flash attention: block = (bh, qblk), 4 waves, 4-way split-K. Each wave
// has a PRIVATE 8KB LDS slice, self-synced (no barriers in the loop).
// 2048 blocks, heavy-first, XCD-pinned bh. Combine via LDS slab reuse.
// =====================================================================
__global__ __launch_bounds__(256) void k_attn(const bf16* __restrict__ qb,
                                              const bf16* __restrict__ kb,
                                              const bf16* __restrict__ vtb,
                                              bf16* __restrict__ yb) {
    const int lane = threadIdx.x & 63;
    const int wv   = threadIdx.x >> 6;   // 0..3
    const int bh   = blockIdx.x;         // 0..31  (XCD = bh % 8)
    const int qblk = 63 - blockIdx.y;    // heavy-first
    const int q0   = qblk * 32;
    const int b    = bh >> 4;
    const int h    = bh & 15;

    const char* Qg = (const char*)(qb  + (size_t)bh * T_SEQ * HEAD_DIM);
    const char* Kg = (const char*)(kb  + (size_t)bh * T_SEQ * HEAD_DIM);
    const char* Vg = (const char*)(vtb + (size_t)bh * HEAD_DIM * T_SEQ);

    const int qr = lane & 31;
    const int hi = lane >> 5;

    __shared__ __align__(16) char sbuf[4][8192];   // per-wave private slice
    __shared__ float ls_l[3][64];
    char* Ks = sbuf[wv];
    char* Vs = sbuf[wv] + 4096;

    // ---- Q fragments: stage via own slice (coalesced), then read ----
    stage_k32(Qg, Ks, qblk * 32, lane);   // Q rows q0..q0+31, same layout as K
    asm volatile("s_waitcnt vmcnt(0)" ::: "memory");
    bf16x8 qf[4];
    {
        const int swzk = (qr & 7) << 4;
        #pragma unroll
        for (int f = 0; f < 4; ++f)
            qf[f] = *reinterpret_cast<const bf16x8*>(
                Ks + ((qr * 128 + f * 32 + hi * 16) ^ swzk));
    }
    // RACE FIX (R17): drain qf ds_reads BEFORE K staging overwrites this LDS.
    lds_fence();

    f32x16 o[2];
    #pragma unroll
    for (int r = 0; r < 16; ++r) { o[0][r] = 0.f; o[1][r] = 0.f; }
    float l_r = 0.f;

    // 4-way split-K: wave wv owns a contiguous chunk; last chunk has diag.
    const int n    = qblk + 1;
    const int base = n >> 2;
    const int rem  = n & 3;
    const int lo   = wv * base + (wv < rem ? wv : rem);
    const int cnt  = base + (wv < rem ? 1 : 0);
    const int end  = lo + cnt;

    for (int t = lo; t < end; ++t) {
        if (t > lo) lds_drain();   // prev tile's ds_reads done before overwrite
        stage_k32(Kg, Ks, t * 32, lane);
        stage_v32(Vg, Vs, t * 32, lane);
        asm volatile("s_waitcnt vmcnt(0)" ::: "memory");
        tile32_w(Ks, Vs, qr, hi, qf, t == qblk, l_r, o);
    }

    // ---- combine across 4 waves: o -> own slab (i-major), plain sums ----
    float* slab = (float*)sbuf[wv];   // 2048 f32 = 64 lanes x 32 exactly
    if (wv > 0) {
        #pragma unroll
        for (int i = 0; i < 16; ++i) {
            slab[i * 64 + lane]        = o[0][i];
            slab[(16 + i) * 64 + lane] = o[1][i];
        }
        ls_l[wv - 1][lane] = l_r;
    }
    __syncthreads();
    if (wv > 0) return;
    #pragma unroll
    for (int s = 1; s < 4; ++s) {
        const float* sl = (const float*)sbuf[s];
        l_r += ls_l[s - 1][lane];
        #pragma unroll
        for (int i = 0; i < 16; ++i) {
            o[0][i] += sl[i * 64 + lane];
            o[1][i] += sl[(16 + i) * 64 + lane];
        }
    }
    l_r = xhalf_sum(l_r);

    // ---- epilogue: O^T[d][q] / l -> y[b][t][h*64+d] ----
    const float inv = 1.f / fmaxf(l_r, 1e-30f);
    const int tq = q0 + qr;
    bf16* yrow = yb + ((size_t)(b * T_SEQ + tq)) * N_EMB + h * HEAD_DIM;
    #pragma unroll
    for (int dt = 0; dt < 2; ++dt) {
        #pragma unroll
        for (int rr = 0; rr < 4; ++rr) {
            const int d0 = dt * 32 + 8 * rr + 4 * hi;
            ushort4 u;
            u.x = f2bu(o[dt][4 * rr + 0] * inv);
            u.y = f2bu(o[dt][4 * rr + 1] * inv);
            u.z = f2bu(o[dt][4 * rr + 2] * inv);
            u.w = f2bu(o[dt][4 * rr + 3] * inv);
            *reinterpret_cast<ushort4*>(yrow + d0) = u;
        }
    }
}

extern "C" void kernel_launch(void* const* d_in, const int* in_sizes, int n_in,
                              void* d_out, int out_size, void* d_ws, size_t ws_size,
                              hipStream_t stream) {
    const float* x      = (const float*)d_in[0];
    const float* W_attn = (const float*)d_in[1];
    const float* b_attn = (const float*)d_in[2];
    const float* W_proj = (const float*)d_in[3];
    const float* b_proj = (const float*)d_in[4];
    float* out = (float*)d_out;

    const size_t sz_x   = (size_t)M_TOT * N_EMB;
    const size_t sz_wat = (size_t)N_QKV * N_EMB;
    const size_t sz_wpt = (size_t)N_EMB * N_EMB;
    const size_t sz_hd  = (size_t)BATCH * N_HEAD * T_SEQ * HEAD_DIM;
    const size_t need = (sz_x + sz_wat + sz_wpt + 3 * sz_hd + sz_x) * sizeof(bf16);
    if (ws_size < need) return;

    bf16* xb  = (bf16*)d_ws;       // dead after QKV GEMM -> reused for V^T
    bf16* wat = xb + sz_x;
    bf16* wpt = wat + sz_wat;
    bf16* qb  = wpt + sz_wpt;
    bf16* kbf = qb + sz_hd;
    bf16* vbf = kbf + sz_hd;
    bf16* yb  = vbf + sz_hd;
    bf16* vtb = xb;                // V^T [B,H,64,T] (k-permuted)

    k_cast<<<dim3((sz_x / 4 + 255) / 256), 256, 0, stream>>>(x, xb, (int)(sz_x / 4));
    k_transpose<<<dim3(N_EMB / 32, N_QKV / 32), 256, 0, stream>>>(W_attn, wat, N_EMB, N_QKV);
    k_transpose<<<dim3(N_EMB / 32, N_EMB / 32), 256, 0, stream>>>(W_proj, wpt, N_EMB, N_EMB);
    k_gemm_qkv<<<dim3(M_TOT / 128, N_QKV / 128), 256, 0, stream>>>(xb, wat, b_attn, qb, kbf, vbf);
    k_vtrans<<<dim3(T_SEQ / 64, BATCH * N_HEAD), 256, 0, stream>>>(vbf, vtb);
    k_attn<<<dim3(BATCH * N_HEAD, 64), 256, 0, stream>>>(qb, kbf, vtb, yb);
    k_gemm_proj<<<dim3(M_TOT / 64, N_EMB / 128), 256, 0, stream>>>(yb, wpt, b_proj, out);
}

// Round 20
// 115.141 us; speedup vs baseline: 1.0967x; 1.0103x over previous
//
#include <hip/hip_runtime.h>
#include <hip/hip_bf16.h>

// ---------------- types ----------------
typedef __bf16 bf16;
typedef __attribute__((ext_vector_type(2))) __bf16 bf16x2;
typedef __attribute__((ext_vector_type(4))) __bf16 bf16x4;
typedef __attribute__((ext_vector_type(8))) __bf16 bf16x8;
typedef __attribute__((ext_vector_type(4))) float f32x4;
typedef __attribute__((ext_vector_type(16))) float f32x16;
typedef unsigned int u32;
typedef __attribute__((ext_vector_type(4))) u32 u32x4;
typedef const __attribute__((address_space(1))) u32* gptr_t;
typedef __attribute__((address_space(3))) u32* lptr_t;

#define N_EMB 1024
#define N_HEAD 16
#define HEAD_DIM 64
#define T_SEQ 2048
#define BATCH 2
#define M_TOT (BATCH * T_SEQ)   // 4096
#define N_QKV (3 * N_EMB)       // 3072
#define KDIM 1024
// scale * log2(e), folded into Q at the QKV epilogue
#define CS_LOG2E 0.1803368801111129f

// round-to-nearest-even f32 -> bf16
__device__ inline unsigned short f2bu(float f) {
    unsigned u = __builtin_bit_cast(unsigned, f);
    return (unsigned short)((u + 0x7fffu + ((u >> 16) & 1u)) >> 16);
}
__device__ inline bf16 f2b(float f) {
    unsigned short s = f2bu(f);
    return __builtin_bit_cast(bf16, s);
}
__device__ inline u32 pkbf(float lo, float hi) {
    bf16x2 t; t[0] = (bf16)lo; t[1] = (bf16)hi;
    return __builtin_bit_cast(u32, t);
}
__device__ __forceinline__ float xhalf_sum(float x) {
    return x + __shfl_xor(x, 32, 64);
}
// full LDS drain + scheduler fence (rule #18): placed after fragment
// ds_reads, before async staging overwrites the same LDS. Nothing
// crosses in either direction.
__device__ __forceinline__ void lds_fence() {
    asm volatile("s_waitcnt lgkmcnt(0)" ::: "memory");
    __builtin_amdgcn_sched_barrier(0);
}

// ---------------- cast x (f32 -> bf16) ----------------
__global__ __launch_bounds__(256) void k_cast(const float* __restrict__ x,
                                              bf16* __restrict__ xb, int n4) {
    int i = blockIdx.x * 256 + threadIdx.x;
    if (i < n4) {
        float4 v = reinterpret_cast<const float4*>(x)[i];
        ushort4 u;
        u.x = f2bu(v.x); u.y = f2bu(v.y); u.z = f2bu(v.z); u.w = f2bu(v.w);
        reinterpret_cast<ushort4*>(xb)[i] = u;
    }
}

// ---------------- transpose + cast: W [K][N] f32 -> Wt [N][K] bf16 ----------------
__global__ __launch_bounds__(256) void k_transpose(const float* __restrict__ W,
                                                   bf16* __restrict__ Wt,
                                                   int K, int N) {
    __shared__ float tile[32][33];
    int k0 = blockIdx.x * 32;
    int n0 = blockIdx.y * 32;
    int tx = threadIdx.x & 31;
    int ty = threadIdx.x >> 5;
    for (int j = 0; j < 32; j += 8)
        tile[ty + j][tx] = W[(k0 + ty + j) * N + n0 + tx];
    __syncthreads();
    for (int j = 0; j < 32; j += 8)
        Wt[(n0 + ty + j) * (long)K + k0 + tx] = f2b(tile[tx][ty + j]);
}

// ---------------- V transpose+k-permute: [B,H,T,64] -> [B,H,64,T'] ----------------
// V'^T[d][t] = V[pi(t)][d]; pi swaps 4-blocks [4,8)<->[8,12) within each
// 16-group of t, matching the PV B-fragment k-order to P's MFMA C-layout
// (pv_group is shuffle-free).
__global__ __launch_bounds__(256) void k_vtrans(const bf16* __restrict__ v,
                                                bf16* __restrict__ vt) {
    __shared__ bf16 tile[64 * 76];
    const int bh = blockIdx.y;
    const int t0 = blockIdx.x * 64;
    const bf16* src = v + (size_t)bh * T_SEQ * HEAD_DIM;
    bf16* dst = vt + (size_t)bh * HEAD_DIM * T_SEQ;
    const int tid = threadIdx.x;
    #pragma unroll
    for (int it = 0; it < 2; ++it) {
        const int row = (tid >> 3) + it * 32;
        const int col = (tid & 7) * 8;
        bf16x8 val = *reinterpret_cast<const bf16x8*>(src + (size_t)(t0 + row) * HEAD_DIM + col);
        bf16x4 lo;  lo[0] = val[0]; lo[1] = val[1]; lo[2] = val[2]; lo[3] = val[3];
        bf16x4 hiv; hiv[0] = val[4]; hiv[1] = val[5]; hiv[2] = val[6]; hiv[3] = val[7];
        *reinterpret_cast<bf16x4*>(&tile[row * 76 + col]) = lo;
        *reinterpret_cast<bf16x4*>(&tile[row * 76 + col + 4]) = hiv;
    }
    __syncthreads();
    #pragma unroll
    for (int it = 0; it < 2; ++it) {
        const int d  = (tid >> 3) + it * 32;
        const int tt = (tid & 7) * 8;
        bf16x8 val;
        #pragma unroll
        for (int q = 0; q < 8; ++q) {
            const int pq = tt + q;
            const int sw = ((pq >> 2) ^ (pq >> 3)) & 1;
            const int ps = sw ? (pq ^ 12) : pq;
            val[q] = tile[ps * 76 + d];
        }
        *reinterpret_cast<bf16x8*>(dst + (size_t)d * T_SEQ + t0 + tt) = val;
    }
}

// =====================================================================
// 128x128 GEMM main loop (m97 structure) — used by QKV
// =====================================================================
#define GEMM_MAINLOOP(A_, Bt_, m0_, n0_)                                          \
    __shared__ __align__(16) bf16 As[128 * 32];                                   \
    __shared__ __align__(16) bf16 Bs[128 * 32];                                   \
    const int lane = threadIdx.x & 63;                                            \
    const int w    = threadIdx.x >> 6;                                            \
    const int wr   = w >> 1;                                                      \
    const int wc   = w & 1;                                                       \
    const int r    = lane & 15;                                                   \
    const int ko   = (lane >> 4) * 8;                                             \
    const int srow = w * 32 + (lane >> 2);                                        \
    const int sk   = (lane & 3) * 8;                                              \
    const bf16* a_g0 = A_ + (size_t)(m0_ + srow) * KDIM + sk;                     \
    const bf16* a_g1 = a_g0 + 16 * KDIM;                                          \
    const bf16* b_g0 = Bt_ + (size_t)(n0_ + srow) * KDIM + sk;                    \
    const bf16* b_g1 = b_g0 + 16 * KDIM;                                          \
    bf16* a_l0 = As + (w * 2) * 512;                                              \
    bf16* a_l1 = As + (w * 2 + 1) * 512;                                          \
    bf16* b_l0 = Bs + (w * 2) * 512;                                              \
    bf16* b_l1 = Bs + (w * 2 + 1) * 512;                                          \
    f32x4 acc[4][4];                                                              \
    for (int i = 0; i < 4; ++i)                                                   \
        for (int j = 0; j < 4; ++j) acc[i][j] = (f32x4){0.f, 0.f, 0.f, 0.f};      \
    for (int k0 = 0; k0 < KDIM; k0 += 32) {                                       \
        __builtin_amdgcn_global_load_lds((gptr_t)(const void*)(a_g0 + k0),        \
                                         (lptr_t)(void*)a_l0, 16, 0, 0);          \
        __builtin_amdgcn_global_load_lds((gptr_t)(const void*)(a_g1 + k0),        \
                                         (lptr_t)(void*)a_l1, 16, 0, 0);          \
        __builtin_amdgcn_global_load_lds((gptr_t)(const void*)(b_g0 + k0),        \
                                         (lptr_t)(void*)b_l0, 16, 0, 0);          \
        __builtin_amdgcn_global_load_lds((gptr_t)(const void*)(b_g1 + k0),        \
                                         (lptr_t)(void*)b_l1, 16, 0, 0);          \
        __syncthreads();                                                          \
        bf16x8 af[4], bfr[4];                                                     \
        for (int m = 0; m < 4; ++m)                                               \
            af[m] = *reinterpret_cast<const bf16x8*>(As + (wr * 64 + m * 16 + r) * 32 + ko); \
        for (int n = 0; n < 4; ++n)                                               \
            bfr[n] = *reinterpret_cast<const bf16x8*>(Bs + (wc * 64 + n * 16 + r) * 32 + ko); \
        for (int m = 0; m < 4; ++m)                                               \
            for (int n = 0; n < 4; ++n)                                           \
                acc[m][n] = __builtin_amdgcn_mfma_f32_16x16x32_bf16(af[m], bfr[n], acc[m][n], 0, 0, 0); \
        __syncthreads();                                                          \
    }

// =====================================================================
// 64x128 GEMM main loop — used by proj
// =====================================================================
#define GEMM_MAINLOOP_64(A_, Bt_, m0_, n0_)                                       \
    __shared__ __align__(16) bf16 As[64 * 32];                                    \
    __shared__ __align__(16) bf16 Bs[128 * 32];                                   \
    const int lane = threadIdx.x & 63;                                            \
    const int w    = threadIdx.x >> 6;                                            \
    const int wr   = w >> 1;                                                      \
    const int wc   = w & 1;                                                       \
    const int r    = lane & 15;                                                   \
    const int ko   = (lane >> 4) * 8;                                             \
    const int srow = w * 16 + (lane >> 2);                                        \
    const int sk   = (lane & 3) * 8;                                              \
    const bf16* a_g0 = A_ + (size_t)(m0_ + srow) * KDIM + sk;                     \
    const bf16* b_g0 = Bt_ + (size_t)(n0_ + srow) * KDIM + sk;                    \
    const bf16* b_g1 = b_g0 + 64 * KDIM;                                          \
    bf16* a_l0 = As + w * 512;                                                    \
    bf16* b_l0 = Bs + w * 512;                                                    \
    bf16* b_l1 = Bs + 64 * 32 + w * 512;                                          \
    f32x4 acc[2][4];                                                              \
    for (int i = 0; i < 2; ++i)                                                   \
        for (int j = 0; j < 4; ++j) acc[i][j] = (f32x4){0.f, 0.f, 0.f, 0.f};      \
    for (int k0 = 0; k0 < KDIM; k0 += 32) {                                       \
        __builtin_amdgcn_global_load_lds((gptr_t)(const void*)(a_g0 + k0),        \
                                         (lptr_t)(void*)a_l0, 16, 0, 0);          \
        __builtin_amdgcn_global_load_lds((gptr_t)(const void*)(b_g0 + k0),        \
                                         (lptr_t)(void*)b_l0, 16, 0, 0);          \
        __builtin_amdgcn_global_load_lds((gptr_t)(const void*)(b_g1 + k0),        \
                                         (lptr_t)(void*)b_l1, 16, 0, 0);          \
        __syncthreads();                                                          \
        bf16x8 af[2], bfr[4];                                                     \
        for (int m = 0; m < 2; ++m)                                               \
            af[m] = *reinterpret_cast<const bf16x8*>(As + (wr * 32 + m * 16 + r) * 32 + ko); \
        for (int n = 0; n < 4; ++n)                                               \
            bfr[n] = *reinterpret_cast<const bf16x8*>(Bs + (wc * 64 + n * 16 + r) * 32 + ko); \
        for (int m = 0; m < 2; ++m)                                               \
            for (int n = 0; n < 4; ++n)                                           \
                acc[m][n] = __builtin_amdgcn_mfma_f32_16x16x32_bf16(af[m], bfr[n], acc[m][n], 0, 0, 0); \
        __syncthreads();                                                          \
    }

// ---------------- QKV GEMM -> q/k/v [B,H,T,64] bf16 (q pre-scaled by CS_LOG2E) ----------------
__global__ __launch_bounds__(256) void k_gemm_qkv(const bf16* __restrict__ A,
                                                  const bf16* __restrict__ Bt,
                                                  const float* __restrict__ bias,
                                                  bf16* __restrict__ qb,
                                                  bf16* __restrict__ kb,
                                                  bf16* __restrict__ vb) {
    const int m0 = blockIdx.x * 128;
    const int n0 = blockIdx.y * 128;
    GEMM_MAINLOOP(A, Bt, m0, n0)
    const int col   = lane & 15;
    const int rbase = (lane >> 4) * 4;
    for (int nn = 0; nn < 4; ++nn) {
        int n = n0 + wc * 64 + nn * 16 + col;
        float bv = bias[n];
        int which = n >> 10;
        int c  = n & 1023;
        int h  = c >> 6;
        int dh = c & 63;
        bf16* dst = (which == 0) ? qb : ((which == 1) ? kb : vb);
        const float sc = (which == 0) ? CS_LOG2E : 1.0f;
        for (int mm = 0; mm < 4; ++mm) {
            for (int i = 0; i < 4; ++i) {
                int m = m0 + wr * 64 + mm * 16 + rbase + i;
                int b_ = m >> 11;
                int t  = m & 2047;
                dst[(((b_ * N_HEAD + h) * T_SEQ) + t) * HEAD_DIM + dh] =
                    f2b((acc[mm][nn][i] + bv) * sc);
            }
        }
    }
}

// ---------------- proj GEMM (64x128 tiles) ----------------
__global__ __launch_bounds__(256) void k_gemm_proj(const bf16* __restrict__ A,
                                                   const bf16* __restrict__ Bt,
                                                   const float* __restrict__ bias,
                                                   float* __restrict__ out) {
    const int m0 = blockIdx.x * 64;
    const int n0 = blockIdx.y * 128;
    GEMM_MAINLOOP_64(A, Bt, m0, n0)
    const int col   = lane & 15;
    const int rbase = (lane >> 4) * 4;
    for (int nn = 0; nn < 4; ++nn) {
        int n = n0 + wc * 64 + nn * 16 + col;
        float bv = bias[n];
        for (int mm = 0; mm < 2; ++mm) {
            for (int i = 0; i < 4; ++i) {
                int m = m0 + wr * 32 + mm * 16 + rbase + i;
                out[(size_t)m * N_EMB + n] = acc[mm][nn][i] + bv;
            }
        }
    }
}

// =====================================================================
// flash attention helpers. Fixed-max softmax (Q pre-scaled, log2 units).
// R20 schedule: per tile, ds_read ALL fragments (kf + va) -> lds_fence
// -> issue tile t+1's global_load_lds into the SAME LDS (safe: reads
// drained) -> compute tile t from regs (covers t+1's HBM latency).
// Loop-top vmcnt(0) then finds tile t+1 resident. No barriers, no
// double-buffer, +32 VGPR live (still 4 waves/SIMD).
// =====================================================================
__device__ __forceinline__ void pv_group(const float* p,
                                         const bf16x8 (&va)[2][2], f32x16 (&o)[2]) {
    u32x4 f0, f1;
    f0[0] = pkbf(p[0], p[1]);   f0[1] = pkbf(p[2], p[3]);
    f0[2] = pkbf(p[4], p[5]);   f0[3] = pkbf(p[6], p[7]);
    f1[0] = pkbf(p[8], p[9]);   f1[1] = pkbf(p[10], p[11]);
    f1[2] = pkbf(p[12], p[13]); f1[3] = pkbf(p[14], p[15]);
    bf16x8 pb0 = __builtin_bit_cast(bf16x8, f0);
    bf16x8 pb1 = __builtin_bit_cast(bf16x8, f1);
    __builtin_amdgcn_s_setprio(1);
    #pragma unroll
    for (int dt = 0; dt < 2; ++dt) {
        o[dt] = __builtin_amdgcn_mfma_f32_32x32x16_bf16(va[dt][0], pb0, o[dt], 0, 0, 0);
        o[dt] = __builtin_amdgcn_mfma_f32_32x32x16_bf16(va[dt][1], pb1, o[dt], 0, 0, 0);
    }
    __builtin_amdgcn_s_setprio(0);
}

// stage one 32-k tile: K 32 rows x 128B (swz (row&7)<<4), V 64 d-rows x 64B
// (swz (d&3)<<4). 4 x 1KB coalesced global_load_lds each.
__device__ __forceinline__ void stage_k32(const char* Kg, char* Ks, int kbase, int lane) {
    #pragma unroll
    for (int rr = 0; rr < 4; ++rr) {
        const int fb  = rr * 1024 + lane * 16;
        const int row = fb >> 7;
        const int swz = (row & 7) << 4;
        __builtin_amdgcn_global_load_lds(
            (gptr_t)(const void*)(Kg + (size_t)kbase * 128 + (fb ^ swz)),
            (lptr_t)(void*)(Ks + rr * 1024), 16, 0, 0);
    }
}
__device__ __forceinline__ void stage_v32(const char* Vg, char* Vs, int kbase, int lane) {
    #pragma unroll
    for (int rr = 0; rr < 4; ++rr) {
        const int fb  = rr * 1024 + lane * 16;
        const int d   = fb >> 6;
        const int off = fb & 63;
        const int swz = (d & 3) << 4;
        __builtin_amdgcn_global_load_lds(
            (gptr_t)(const void*)(Vg + (size_t)d * (T_SEQ * 2) + (size_t)kbase * 2 + (off ^ swz)),
            (lptr_t)(void*)(Vs + rr * 1024), 16, 0, 0);
    }
}

// ds_read all fragments for one tile into registers
__device__ __forceinline__ void load_frags(const char* Ks, const char* Vs,
                                           int qr, int hi,
                                           bf16x8 (&kf)[4], bf16x8 (&va)[2][2]) {
    const int swzk = (qr & 7) << 4;
    #pragma unroll
    for (int f = 0; f < 4; ++f)
        kf[f] = *reinterpret_cast<const bf16x8*>(
            Ks + ((qr * 128 + f * 32 + hi * 16) ^ swzk));
    #pragma unroll
    for (int dt = 0; dt < 2; ++dt)
        #pragma unroll
        for (int ks = 0; ks < 2; ++ks) {
            const int d = dt * 32 + qr;
            va[dt][ks] = *reinterpret_cast<const bf16x8*>(
                Vs + ((d * 64 + ks * 32 + hi * 16) ^ ((d & 3) << 4)));
        }
}

// compute one tile entirely from registers
__device__ __forceinline__ void compute_tile(const bf16x8 (&kf)[4],
                                             const bf16x8 (&va)[2][2],
                                             int qr, int hi, const bf16x8 (&qf)[4],
                                             bool diag, float& l_r, f32x16 (&o)[2]) {
    f32x16 st;
    #pragma unroll
    for (int r = 0; r < 16; ++r) st[r] = 0.f;
    __builtin_amdgcn_s_setprio(1);
    #pragma unroll
    for (int f = 0; f < 4; ++f)
        st = __builtin_amdgcn_mfma_f32_32x32x16_bf16(kf[f], qf[f], st, 0, 0, 0);
    __builtin_amdgcn_s_setprio(0);
    if (diag) {
        const int kp4 = 4 * hi;
        #pragma unroll
        for (int r = 0; r < 16; ++r) {
            const int kpos = (r & 3) + 8 * (r >> 2) + kp4;
            if (kpos > qr) st[r] = -3.0e38f;
        }
    }
    float p[16];
    #pragma unroll
    for (int r = 0; r < 16; ++r) p[r] = exp2f(st[r]);   // masked -3e38 underflows to 0
    float s = 0.f;
    #pragma unroll
    for (int r = 0; r < 8; ++r) s += p[r] + p[r + 8];
    l_r += s;
    pv_group(p, va, o);
}

// =====================================================================
// flash attention: block = (bh, qblk), 4 waves, 4-way split-K. Each wave
// has a PRIVATE 8KB LDS slice, self-synced (no barriers in the loop).
// Staging of tile t+1 overlaps compute of tile t (fragments in regs).
// 2048 blocks, heavy-first, XCD-pinned bh. Combine via LDS slab reuse.
// =====================================================================
__global__ __launch_bounds__(256) void k_attn(const bf16* __restrict__ qb,
                                              const bf16* __restrict__ kb,
                                              const bf16* __restrict__ vtb,
                                              bf16* __restrict__ yb) {
    const int lane = threadIdx.x & 63;
    const int wv   = threadIdx.x >> 6;   // 0..3
    const int bh   = blockIdx.x;         // 0..31  (XCD = bh % 8)
    const int qblk = 63 - blockIdx.y;    // heavy-first
    const int q0   = qblk * 32;
    const int b    = bh >> 4;
    const int h    = bh & 15;

    const char* Qg = (const char*)(qb  + (size_t)bh * T_SEQ * HEAD_DIM);
    const char* Kg = (const char*)(kb  + (size_t)bh * T_SEQ * HEAD_DIM);
    const char* Vg = (const char*)(vtb + (size_t)bh * HEAD_DIM * T_SEQ);

    const int qr = lane & 31;
    const int hi = lane >> 5;

    __shared__ __align__(16) char sbuf[4][8192];   // per-wave private slice
    __shared__ float ls_l[3][64];
    char* Ks = sbuf[wv];
    char* Vs = sbuf[wv] + 4096;

    // ---- Q fragments: stage via own slice (coalesced), then read ----
    stage_k32(Qg, Ks, qblk * 32, lane);   // Q rows q0..q0+31, same layout as K
    asm volatile("s_waitcnt vmcnt(0)" ::: "memory");
    bf16x8 qf[4];
    {
        const int swzk = (qr & 7) << 4;
        #pragma unroll
        for (int f = 0; f < 4; ++f)
            qf[f] = *reinterpret_cast<const bf16x8*>(
                Ks + ((qr * 128 + f * 32 + hi * 16) ^ swzk));
    }
    // RACE FIX (R17): drain qf ds_reads BEFORE K staging overwrites this LDS.
    lds_fence();

    f32x16 o[2];
    #pragma unroll
    for (int r = 0; r < 16; ++r) { o[0][r] = 0.f; o[1][r] = 0.f; }
    float l_r = 0.f;

    // 4-way split-K: wave wv owns a contiguous chunk; last chunk has diag.
    const int n    = qblk + 1;
    const int base = n >> 2;
    const int rem  = n & 3;
    const int lo   = wv * base + (wv < rem ? wv : rem);
    const int cnt  = base + (wv < rem ? 1 : 0);
    const int end  = lo + cnt;

    if (cnt > 0) {
        stage_k32(Kg, Ks, lo * 32, lane);
        stage_v32(Vg, Vs, lo * 32, lane);
        for (int t = lo; t < end; ++t) {
            asm volatile("s_waitcnt vmcnt(0)" ::: "memory");   // tile t resident
            bf16x8 kf[4], va[2][2];
            load_frags(Ks, Vs, qr, hi, kf, va);
            lds_fence();                       // reads drained; nothing crosses
            if (t + 1 < end) {                 // stage t+1 under compute of t
                stage_k32(Kg, Ks, (t + 1) * 32, lane);
                stage_v32(Vg, Vs, (t + 1) * 32, lane);
            }
            compute_tile(kf, va, qr, hi, qf, t == qblk, l_r, o);
        }
    }

    // ---- combine across 4 waves: o -> own slab (i-major), plain sums ----
    float* slab = (float*)sbuf[wv];   // 2048 f32 = 64 lanes x 32 exactly
    if (wv > 0) {
        #pragma unroll
        for (int i = 0; i < 16; ++i) {
            slab[i * 64 + lane]        = o[0][i];
            slab[(16 + i) * 64 + lane] = o[1][i];
        }
        ls_l[wv - 1][lane] = l_r;
    }
    __syncthreads();
    if (wv > 0) return;
    #pragma unroll
    for (int s = 1; s < 4; ++s) {
        const float* sl = (const float*)sbuf[s];
        l_r += ls_l[s - 1][lane];
        #pragma unroll
        for (int i = 0; i < 16; ++i) {
            o[0][i] += sl[i * 64 + lane];
            o[1][i] += sl[(16 + i) * 64 + lane];
        }
    }
    l_r = xhalf_sum(l_r);

    // ---- epilogue: O^T[d][q] / l -> y[b][t][h*64+d] ----
    const float inv = 1.f / fmaxf(l_r, 1e-30f);
    const int tq = q0 + qr;
    bf16* yrow = yb + ((size_t)(b * T_SEQ + tq)) * N_EMB + h * HEAD_DIM;
    #pragma unroll
    for (int dt = 0; dt < 2; ++dt) {
        #pragma unroll
        for (int rr = 0; rr < 4; ++rr) {
            const int d0 = dt * 32 + 8 * rr + 4 * hi;
            ushort4 u;
            u.x = f2bu(o[dt][4 * rr + 0] * inv);
            u.y = f2bu(o[dt][4 * rr + 1] * inv);
            u.z = f2bu(o[dt][4 * rr + 2] * inv);
            u.w = f2bu(o[dt][4 * rr + 3] * inv);
            *reinterpret_cast<ushort4*>(yrow + d0) = u;
        }
    }
}

extern "C" void kernel_launch(void* const* d_in, const int* in_sizes, int n_in,
                              void* d_out, int out_size, void* d_ws, size_t ws_size,
                              hipStream_t stream) {
    const float* x      = (const float*)d_in[0];
    const float* W_attn = (const float*)d_in[1];
    const float* b_attn = (const float*)d_in[2];
    const float* W_proj = (const float*)d_in[3];
    const float* b_proj = (const float*)d_in[4];
    float* out = (float*)d_out;

    const size_t sz_x   = (size_t)M_TOT * N_EMB;
    const size_t sz_wat = (size_t)N_QKV * N_EMB;
    const size_t sz_wpt = (size_t)N_EMB * N_EMB;
    const size_t sz_hd  = (size_t)BATCH * N_HEAD * T_SEQ * HEAD_DIM;
    const size_t need = (sz_x + sz_wat + sz_wpt + 3 * sz_hd + sz_x) * sizeof(bf16);
    if (ws_size < need) return;

    bf16* xb  = (bf16*)d_ws;       // dead after QKV GEMM -> reused for V^T
    bf16* wat = xb + sz_x;
    bf16* wpt = wat + sz_wat;
    bf16* qb  = wpt + sz_wpt;
    bf16* kbf = qb + sz_hd;
    bf16* vbf = kbf + sz_hd;
    bf16* yb  = vbf + sz_hd;
    bf16* vtb = xb;                // V^T [B,H,64,T] (k-permuted)

    k_cast<<<dim3((sz_x / 4 + 255) / 256), 256, 0, stream>>>(x, xb, (int)(sz_x / 4));
    k_transpose<<<dim3(N_EMB / 32, N_QKV / 32), 256, 0, stream>>>(W_attn, wat, N_EMB, N_QKV);
    k_transpose<<<dim3(N_EMB / 32, N_EMB / 32), 256, 0, stream>>>(W_proj, wpt, N_EMB, N_EMB);
    k_gemm_qkv<<<dim3(M_TOT / 128, N_QKV / 128), 256, 0, stream>>>(xb, wat, b_attn, qb, kbf, vbf);
    k_vtrans<<<dim3(T_SEQ / 64, BATCH * N_HEAD), 256, 0, stream>>>(vbf, vtb);
    k_attn<<<dim3(BATCH * N_HEAD, 64), 256, 0, stream>>>(qb, kbf, vtb, yb);
    k_gemm_proj<<<dim3(M_TOT / 64, N_EMB / 128), 256, 0, stream>>>(yb, wpt, b_proj, out);
}

// Round 21
// 112.217 us; speedup vs baseline: 1.1252x; 1.0261x over previous
//
#include <hip/hip_runtime.h>
#include <hip/hip_bf16.h>

// ---------------- types ----------------
typedef __bf16 bf16;
typedef __attribute__((ext_vector_type(2))) __bf16 bf16x2;
typedef __attribute__((ext_vector_type(4))) __bf16 bf16x4;
typedef __attribute__((ext_vector_type(8))) __bf16 bf16x8;
typedef __attribute__((ext_vector_type(4))) float f32x4;
typedef __attribute__((ext_vector_type(16))) float f32x16;
typedef unsigned int u32;
typedef __attribute__((ext_vector_type(4))) u32 u32x4;
typedef const __attribute__((address_space(1))) u32* gptr_t;
typedef __attribute__((address_space(3))) u32* lptr_t;

#define N_EMB 1024
#define N_HEAD 16
#define HEAD_DIM 64
#define T_SEQ 2048
#define BATCH 2
#define M_TOT (BATCH * T_SEQ)   // 4096
#define N_QKV (3 * N_EMB)       // 3072
#define KDIM 1024
// scale * log2(e), folded into Q at the QKV epilogue
#define CS_LOG2E 0.1803368801111129f

// round-to-nearest-even f32 -> bf16
__device__ inline unsigned short f2bu(float f) {
    unsigned u = __builtin_bit_cast(unsigned, f);
    return (unsigned short)((u + 0x7fffu + ((u >> 16) & 1u)) >> 16);
}
__device__ inline bf16 f2b(float f) {
    unsigned short s = f2bu(f);
    return __builtin_bit_cast(bf16, s);
}
__device__ inline u32 pkbf(float lo, float hi) {
    bf16x2 t; t[0] = (bf16)lo; t[1] = (bf16)hi;
    return __builtin_bit_cast(u32, t);
}
__device__ __forceinline__ float xhalf_sum(float x) {
    return x + __shfl_xor(x, 32, 64);
}
// full LDS drain + scheduler fence (rule #18): placed after fragment
// ds_reads, before async staging overwrites the same LDS.
__device__ __forceinline__ void lds_fence() {
    asm volatile("s_waitcnt lgkmcnt(0)" ::: "memory");
    __builtin_amdgcn_sched_barrier(0);
}

// ---------------- fused prep: cast x + transpose both weights ----------------
// blocks [0,4096): cast x f32->bf16 (4 elems/thread)
// blocks [4096,7168): W_attn [1024][3072] -> wat [3072][1024] bf16
// blocks [7168,8192): W_proj [1024][1024] -> wpt [1024][1024] bf16
__global__ __launch_bounds__(256) void k_prep(const float* __restrict__ x,
                                              const float* __restrict__ W_attn,
                                              const float* __restrict__ W_proj,
                                              bf16* __restrict__ xb,
                                              bf16* __restrict__ wat,
                                              bf16* __restrict__ wpt) {
    const int id = blockIdx.x;
    if (id < 4096) {
        int i = id * 256 + threadIdx.x;
        float4 v = reinterpret_cast<const float4*>(x)[i];
        ushort4 u;
        u.x = f2bu(v.x); u.y = f2bu(v.y); u.z = f2bu(v.z); u.w = f2bu(v.w);
        reinterpret_cast<ushort4*>(xb)[i] = u;
        return;
    }
    __shared__ float tile[32][33];
    const float* W; bf16* Wt; int N, bid;
    if (id < 7168) { W = W_attn; Wt = wat; N = N_QKV; bid = id - 4096; }
    else           { W = W_proj; Wt = wpt; N = N_EMB; bid = id - 7168; }
    const int k0 = (bid & 31) * 32;
    const int n0 = (bid >> 5) * 32;
    const int tx = threadIdx.x & 31;
    const int ty = threadIdx.x >> 5;
    for (int j = 0; j < 32; j += 8)
        tile[ty + j][tx] = W[(k0 + ty + j) * N + n0 + tx];
    __syncthreads();
    for (int j = 0; j < 32; j += 8)
        Wt[(n0 + ty + j) * (long)KDIM + k0 + tx] = f2b(tile[tx][ty + j]);
}

// ---------------- V transpose+k-permute: [B,H,T,64] -> [B,H,64,T'] ----------------
// V'^T[d][t] = V[pi(t)][d]; pi swaps 4-blocks [4,8)<->[8,12) within each
// 16-group of t, matching the PV B-fragment k-order to P's MFMA C-layout
// (pv_group is shuffle-free).
__global__ __launch_bounds__(256) void k_vtrans(const bf16* __restrict__ v,
                                                bf16* __restrict__ vt) {
    __shared__ bf16 tile[64 * 76];
    const int bh = blockIdx.y;
    const int t0 = blockIdx.x * 64;
    const bf16* src = v + (size_t)bh * T_SEQ * HEAD_DIM;
    bf16* dst = vt + (size_t)bh * HEAD_DIM * T_SEQ;
    const int tid = threadIdx.x;
    #pragma unroll
    for (int it = 0; it < 2; ++it) {
        const int row = (tid >> 3) + it * 32;
        const int col = (tid & 7) * 8;
        bf16x8 val = *reinterpret_cast<const bf16x8*>(src + (size_t)(t0 + row) * HEAD_DIM + col);
        bf16x4 lo;  lo[0] = val[0]; lo[1] = val[1]; lo[2] = val[2]; lo[3] = val[3];
        bf16x4 hiv; hiv[0] = val[4]; hiv[1] = val[5]; hiv[2] = val[6]; hiv[3] = val[7];
        *reinterpret_cast<bf16x4*>(&tile[row * 76 + col]) = lo;
        *reinterpret_cast<bf16x4*>(&tile[row * 76 + col + 4]) = hiv;
    }
    __syncthreads();
    #pragma unroll
    for (int it = 0; it < 2; ++it) {
        const int d  = (tid >> 3) + it * 32;
        const int tt = (tid & 7) * 8;
        bf16x8 val;
        #pragma unroll
        for (int q = 0; q < 8; ++q) {
            const int pq = tt + q;
            const int sw = ((pq >> 2) ^ (pq >> 3)) & 1;
            const int ps = sw ? (pq ^ 12) : pq;
            val[q] = tile[ps * 76 + d];
        }
        *reinterpret_cast<bf16x8*>(dst + (size_t)d * T_SEQ + t0 + tt) = val;
    }
}

// =====================================================================
// 128x128 GEMM main loop (m97 structure) — used by QKV
// =====================================================================
#define GEMM_MAINLOOP(A_, Bt_, m0_, n0_)                                          \
    __shared__ __align__(16) bf16 As[128 * 32];                                   \
    __shared__ __align__(16) bf16 Bs[128 * 32];                                   \
    const int lane = threadIdx.x & 63;                                            \
    const int w    = threadIdx.x >> 6;                                            \
    const int wr   = w >> 1;                                                      \
    const int wc   = w & 1;                                                       \
    const int r    = lane & 15;                                                   \
    const int ko   = (lane >> 4) * 8;                                             \
    const int srow = w * 32 + (lane >> 2);                                        \
    const int sk   = (lane & 3) * 8;                                              \
    const bf16* a_g0 = A_ + (size_t)(m0_ + srow) * KDIM + sk;                     \
    const bf16* a_g1 = a_g0 + 16 * KDIM;                                          \
    const bf16* b_g0 = Bt_ + (size_t)(n0_ + srow) * KDIM + sk;                    \
    const bf16* b_g1 = b_g0 + 16 * KDIM;                                          \
    bf16* a_l0 = As + (w * 2) * 512;                                              \
    bf16* a_l1 = As + (w * 2 + 1) * 512;                                          \
    bf16* b_l0 = Bs + (w * 2) * 512;                                              \
    bf16* b_l1 = Bs + (w * 2 + 1) * 512;                                          \
    f32x4 acc[4][4];                                                              \
    for (int i = 0; i < 4; ++i)                                                   \
        for (int j = 0; j < 4; ++j) acc[i][j] = (f32x4){0.f, 0.f, 0.f, 0.f};      \
    for (int k0 = 0; k0 < KDIM; k0 += 32) {                                       \
        __builtin_amdgcn_global_load_lds((gptr_t)(const void*)(a_g0 + k0),        \
                                         (lptr_t)(void*)a_l0, 16, 0, 0);          \
        __builtin_amdgcn_global_load_lds((gptr_t)(const void*)(a_g1 + k0),        \
                                         (lptr_t)(void*)a_l1, 16, 0, 0);          \
        __builtin_amdgcn_global_load_lds((gptr_t)(const void*)(b_g0 + k0),        \
                                         (lptr_t)(void*)b_l0, 16, 0, 0);          \
        __builtin_amdgcn_global_load_lds((gptr_t)(const void*)(b_g1 + k0),        \
                                         (lptr_t)(void*)b_l1, 16, 0, 0);          \
        __syncthreads();                                                          \
        bf16x8 af[4], bfr[4];                                                     \
        for (int m = 0; m < 4; ++m)                                               \
            af[m] = *reinterpret_cast<const bf16x8*>(As + (wr * 64 + m * 16 + r) * 32 + ko); \
        for (int n = 0; n < 4; ++n)                                               \
            bfr[n] = *reinterpret_cast<const bf16x8*>(Bs + (wc * 64 + n * 16 + r) * 32 + ko); \
        for (int m = 0; m < 4; ++m)                                               \
            for (int n = 0; n < 4; ++n)                                           \
                acc[m][n] = __builtin_amdgcn_mfma_f32_16x16x32_bf16(af[m], bfr[n], acc[m][n], 0, 0, 0); \
        __syncthreads();                                                          \
    }

// =====================================================================
// 64x128 GEMM main loop — used by proj
// =====================================================================
#define GEMM_MAINLOOP_64(A_, Bt_, m0_, n0_)                                       \
    __shared__ __align__(16) bf16 As[64 * 32];                                    \
    __shared__ __align__(16) bf16 Bs[128 * 32];                                   \
    const int lane = threadIdx.x & 63;                                            \
    const int w    = threadIdx.x >> 6;                                            \
    const int wr   = w >> 1;                                                      \
    const int wc   = w & 1;                                                       \
    const int r    = lane & 15;                                                   \
    const int ko   = (lane >> 4) * 8;                                             \
    const int srow = w * 16 + (lane >> 2);                                        \
    const int sk   = (lane & 3) * 8;                                              \
    const bf16* a_g0 = A_ + (size_t)(m0_ + srow) * KDIM + sk;                     \
    const bf16* b_g0 = Bt_ + (size_t)(n0_ + srow) * KDIM + sk;                    \
    const bf16* b_g1 = b_g0 + 64 * KDIM;                                          \
    bf16* a_l0 = As + w * 512;                                                    \
    bf16* b_l0 = Bs + w * 512;                                                    \
    bf16* b_l1 = Bs + 64 * 32 + w * 512;                                          \
    f32x4 acc[2][4];                                                              \
    for (int i = 0; i < 2; ++i)                                                   \
        for (int j = 0; j < 4; ++j) acc[i][j] = (f32x4){0.f, 0.f, 0.f, 0.f};      \
    for (int k0 = 0; k0 < KDIM; k0 += 32) {                                       \
        __builtin_amdgcn_global_load_lds((gptr_t)(const void*)(a_g0 + k0),        \
                                         (lptr_t)(void*)a_l0, 16, 0, 0);          \
        __builtin_amdgcn_global_load_lds((gptr_t)(const void*)(b_g0 + k0),        \
                                         (lptr_t)(void*)b_l0, 16, 0, 0);          \
        __builtin_amdgcn_global_load_lds((gptr_t)(const void*)(b_g1 + k0),        \
                                         (lptr_t)(void*)b_l1, 16, 0, 0);          \
        __syncthreads();                                                          \
        bf16x8 af[2], bfr[4];                                                     \
        for (int m = 0; m < 2; ++m)                                               \
            af[m] = *reinterpret_cast<const bf16x8*>(As + (wr * 32 + m * 16 + r) * 32 + ko); \
        for (int n = 0; n < 4; ++n)                                               \
            bfr[n] = *reinterpret_cast<const bf16x8*>(Bs + (wc * 64 + n * 16 + r) * 32 + ko); \
        for (int m = 0; m < 2; ++m)                                               \
            for (int n = 0; n < 4; ++n)                                           \
                acc[m][n] = __builtin_amdgcn_mfma_f32_16x16x32_bf16(af[m], bfr[n], acc[m][n], 0, 0, 0); \
        __syncthreads();                                                          \
    }

// ---------------- QKV GEMM -> q/k/v [B,H,T,64] bf16 (q pre-scaled by CS_LOG2E) ----------------
__global__ __launch_bounds__(256) void k_gemm_qkv(const bf16* __restrict__ A,
                                                  const bf16* __restrict__ Bt,
                                                  const float* __restrict__ bias,
                                                  bf16* __restrict__ qb,
                                                  bf16* __restrict__ kb,
                                                  bf16* __restrict__ vb) {
    const int m0 = blockIdx.x * 128;
    const int n0 = blockIdx.y * 128;
    GEMM_MAINLOOP(A, Bt, m0, n0)
    const int col   = lane & 15;
    const int rbase = (lane >> 4) * 4;
    for (int nn = 0; nn < 4; ++nn) {
        int n = n0 + wc * 64 + nn * 16 + col;
        float bv = bias[n];
        int which = n >> 10;
        int c  = n & 1023;
        int h  = c >> 6;
        int dh = c & 63;
        bf16* dst = (which == 0) ? qb : ((which == 1) ? kb : vb);
        const float sc = (which == 0) ? CS_LOG2E : 1.0f;
        for (int mm = 0; mm < 4; ++mm) {
            for (int i = 0; i < 4; ++i) {
                int m = m0 + wr * 64 + mm * 16 + rbase + i;
                int b_ = m >> 11;
                int t  = m & 2047;
                dst[(((b_ * N_HEAD + h) * T_SEQ) + t) * HEAD_DIM + dh] =
                    f2b((acc[mm][nn][i] + bv) * sc);
            }
        }
    }
}

// ---------------- proj GEMM (64x128 tiles) ----------------
__global__ __launch_bounds__(256) void k_gemm_proj(const bf16* __restrict__ A,
                                                   const bf16* __restrict__ Bt,
                                                   const float* __restrict__ bias,
                                                   float* __restrict__ out) {
    const int m0 = blockIdx.x * 64;
    const int n0 = blockIdx.y * 128;
    GEMM_MAINLOOP_64(A, Bt, m0, n0)
    const int col   = lane & 15;
    const int rbase = (lane >> 4) * 4;
    for (int nn = 0; nn < 4; ++nn) {
        int n = n0 + wc * 64 + nn * 16 + col;
        float bv = bias[n];
        for (int mm = 0; mm < 2; ++mm) {
            for (int i = 0; i < 4; ++i) {
                int m = m0 + wr * 32 + mm * 16 + rbase + i;
                out[(size_t)m * N_EMB + n] = acc[mm][nn][i] + bv;
            }
        }
    }
}

// =====================================================================
// flash attention helpers. Fixed-max softmax (Q pre-scaled, log2 units).
// R20 schedule (proven): per tile, ds_read all fragments -> lds_fence ->
// stage t+1 into same LDS -> compute t from regs. R21: combine slabs in
// bf16 + l packed into slab region -> LDS exactly 32KB -> 5 blocks/CU.
// =====================================================================
__device__ __forceinline__ void pv_group(const float* p,
                                         const bf16x8 (&va)[2][2], f32x16 (&o)[2]) {
    u32x4 f0, f1;
    f0[0] = pkbf(p[0], p[1]);   f0[1] = pkbf(p[2], p[3]);
    f0[2] = pkbf(p[4], p[5]);   f0[3] = pkbf(p[6], p[7]);
    f1[0] = pkbf(p[8], p[9]);   f1[1] = pkbf(p[10], p[11]);
    f1[2] = pkbf(p[12], p[13]); f1[3] = pkbf(p[14], p[15]);
    bf16x8 pb0 = __builtin_bit_cast(bf16x8, f0);
    bf16x8 pb1 = __builtin_bit_cast(bf16x8, f1);
    __builtin_amdgcn_s_setprio(1);
    #pragma unroll
    for (int dt = 0; dt < 2; ++dt) {
        o[dt] = __builtin_amdgcn_mfma_f32_32x32x16_bf16(va[dt][0], pb0, o[dt], 0, 0, 0);
        o[dt] = __builtin_amdgcn_mfma_f32_32x32x16_bf16(va[dt][1], pb1, o[dt], 0, 0, 0);
    }
    __builtin_amdgcn_s_setprio(0);
}

// stage one 32-k tile: K 32 rows x 128B (swz (row&7)<<4), V 64 d-rows x 64B
// (swz (d&3)<<4). 4 x 1KB coalesced global_load_lds each.
__device__ __forceinline__ void stage_k32(const char* Kg, char* Ks, int kbase, int lane) {
    #pragma unroll
    for (int rr = 0; rr < 4; ++rr) {
        const int fb  = rr * 1024 + lane * 16;
        const int row = fb >> 7;
        const int swz = (row & 7) << 4;
        __builtin_amdgcn_global_load_lds(
            (gptr_t)(const void*)(Kg + (size_t)kbase * 128 + (fb ^ swz)),
            (lptr_t)(void*)(Ks + rr * 1024), 16, 0, 0);
    }
}
__device__ __forceinline__ void stage_v32(const char* Vg, char* Vs, int kbase, int lane) {
    #pragma unroll
    for (int rr = 0; rr < 4; ++rr) {
        const int fb  = rr * 1024 + lane * 16;
        const int d   = fb >> 6;
        const int off = fb & 63;
        const int swz = (d & 3) << 4;
        __builtin_amdgcn_global_load_lds(
            (gptr_t)(const void*)(Vg + (size_t)d * (T_SEQ * 2) + (size_t)kbase * 2 + (off ^ swz)),
            (lptr_t)(void*)(Vs + rr * 1024), 16, 0, 0);
    }
}

// ds_read all fragments for one tile into registers
__device__ __forceinline__ void load_frags(const char* Ks, const char* Vs,
                                           int qr, int hi,
                                           bf16x8 (&kf)[4], bf16x8 (&va)[2][2]) {
    const int swzk = (qr & 7) << 4;
    #pragma unroll
    for (int f = 0; f < 4; ++f)
        kf[f] = *reinterpret_cast<const bf16x8*>(
            Ks + ((qr * 128 + f * 32 + hi * 16) ^ swzk));
    #pragma unroll
    for (int dt = 0; dt < 2; ++dt)
        #pragma unroll
        for (int ks = 0; ks < 2; ++ks) {
            const int d = dt * 32 + qr;
            va[dt][ks] = *reinterpret_cast<const bf16x8*>(
                Vs + ((d * 64 + ks * 32 + hi * 16) ^ ((d & 3) << 4)));
        }
}

// compute one tile entirely from registers
__device__ __forceinline__ void compute_tile(const bf16x8 (&kf)[4],
                                             const bf16x8 (&va)[2][2],
                                             int qr, int hi, const bf16x8 (&qf)[4],
                                             bool diag, float& l_r, f32x16 (&o)[2]) {
    f32x16 st;
    #pragma unroll
    for (int r = 0; r < 16; ++r) st[r] = 0.f;
    __builtin_amdgcn_s_setprio(1);
    #pragma unroll
    for (int f = 0; f < 4; ++f)
        st = __builtin_amdgcn_mfma_f32_32x32x16_bf16(kf[f], qf[f], st, 0, 0, 0);
    __builtin_amdgcn_s_setprio(0);
    if (diag) {
        const int kp4 = 4 * hi;
        #pragma unroll
        for (int r = 0; r < 16; ++r) {
            const int kpos = (r & 3) + 8 * (r >> 2) + kp4;
            if (kpos > qr) st[r] = -3.0e38f;
        }
    }
    float p[16];
    #pragma unroll
    for (int r = 0; r < 16; ++r) p[r] = exp2f(st[r]);   // masked -3e38 underflows to 0
    float s = 0.f;
    #pragma unroll
    for (int r = 0; r < 8; ++r) s += p[r] + p[r + 8];
    l_r += s;
    pv_group(p, va, o);
}

// =====================================================================
// flash attention: block = (bh, qblk), 4 waves, 4-way split-K. Each wave
// has a PRIVATE 8KB LDS slice, self-synced (no barriers in the loop).
// Staging of tile t+1 overlaps compute of tile t (fragments in regs).
// Combine: slabs in bf16 (4KB) + l f32 (256B) packed into own slice ->
// LDS exactly 32KB -> 5 blocks/CU (20 waves). 2048 blocks, heavy-first,
// XCD-pinned bh.
// =====================================================================
__global__ __launch_bounds__(256) void k_attn(const bf16* __restrict__ qb,
                                              const bf16* __restrict__ kb,
                                              const bf16* __restrict__ vtb,
                                              bf16* __restrict__ yb) {
    const int lane = threadIdx.x & 63;
    const int wv   = threadIdx.x >> 6;   // 0..3
    const int bh   = blockIdx.x;         // 0..31  (XCD = bh % 8)
    const int qblk = 63 - blockIdx.y;    // heavy-first
    const int q0   = qblk * 32;
    const int b    = bh >> 4;
    const int h    = bh & 15;

    const char* Qg = (const char*)(qb  + (size_t)bh * T_SEQ * HEAD_DIM);
    const char* Kg = (const char*)(kb  + (size_t)bh * T_SEQ * HEAD_DIM);
    const char* Vg = (const char*)(vtb + (size_t)bh * HEAD_DIM * T_SEQ);

    const int qr = lane & 31;
    const int hi = lane >> 5;

    __shared__ __align__(16) char sbuf[4][8192];   // per-wave private slice; 32KB total
    char* Ks = sbuf[wv];
    char* Vs = sbuf[wv] + 4096;

    // ---- Q fragments: stage via own slice (coalesced), then read ----
    stage_k32(Qg, Ks, qblk * 32, lane);   // Q rows q0..q0+31, same layout as K
    asm volatile("s_waitcnt vmcnt(0)" ::: "memory");
    bf16x8 qf[4];
    {
        const int swzk = (qr & 7) << 4;
        #pragma unroll
        for (int f = 0; f < 4; ++f)
            qf[f] = *reinterpret_cast<const bf16x8*>(
                Ks + ((qr * 128 + f * 32 + hi * 16) ^ swzk));
    }
    // RACE FIX (R17): drain qf ds_reads BEFORE K staging overwrites this LDS.
    lds_fence();

    f32x16 o[2];
    #pragma unroll
    for (int r = 0; r < 16; ++r) { o[0][r] = 0.f; o[1][r] = 0.f; }
    float l_r = 0.f;

    // 4-way split-K: wave wv owns a contiguous chunk; last chunk has diag.
    const int n    = qblk + 1;
    const int base = n >> 2;
    const int rem  = n & 3;
    const int lo   = wv * base + (wv < rem ? wv : rem);
    const int cnt  = base + (wv < rem ? 1 : 0);
    const int end  = lo + cnt;

    if (cnt > 0) {
        stage_k32(Kg, Ks, lo * 32, lane);
        stage_v32(Vg, Vs, lo * 32, lane);
        for (int t = lo; t < end; ++t) {
            asm volatile("s_waitcnt vmcnt(0)" ::: "memory");   // tile t resident
            bf16x8 kf[4], va[2][2];
            load_frags(Ks, Vs, qr, hi, kf, va);
            lds_fence();                       // reads drained; nothing crosses
            if (t + 1 < end) {                 // stage t+1 under compute of t
                stage_k32(Kg, Ks, (t + 1) * 32, lane);
                stage_v32(Vg, Vs, (t + 1) * 32, lane);
            }
            compute_tile(kf, va, qr, hi, qf, t == qblk, l_r, o);
        }
    }

    // ---- combine across 4 waves via own slice: bf16 o slab + f32 l ----
    // slab layout: [0,4096) bf16 o (index i*64+lane), [4096,4352) f32 l.
    if (wv > 0) {
        bf16* so = (bf16*)sbuf[wv];
        #pragma unroll
        for (int i = 0; i < 16; ++i) {
            so[i * 64 + lane]        = f2b(o[0][i]);
            so[(16 + i) * 64 + lane] = f2b(o[1][i]);
        }
        *reinterpret_cast<float*>(sbuf[wv] + 4096 + lane * 4) = l_r;
    }
    __syncthreads();
    if (wv > 0) return;
    #pragma unroll
    for (int s = 1; s < 4; ++s) {
        const bf16* so = (const bf16*)sbuf[s];
        l_r += *reinterpret_cast<const float*>(sbuf[s] + 4096 + lane * 4);
        #pragma unroll
        for (int i = 0; i < 16; ++i) {
            o[0][i] += (float)so[i * 64 + lane];
            o[1][i] += (float)so[(16 + i) * 64 + lane];
        }
    }
    l_r = xhalf_sum(l_r);

    // ---- epilogue: O^T[d][q] / l -> y[b][t][h*64+d] ----
    const float inv = 1.f / fmaxf(l_r, 1e-30f);
    const int tq = q0 + qr;
    bf16* yrow = yb + ((size_t)(b * T_SEQ + tq)) * N_EMB + h * HEAD_DIM;
    #pragma unroll
    for (int dt = 0; dt < 2; ++dt) {
        #pragma unroll
        for (int rr = 0; rr < 4; ++rr) {
            const int d0 = dt * 32 + 8 * rr + 4 * hi;
            ushort4 u;
            u.x = f2bu(o[dt][4 * rr + 0] * inv);
            u.y = f2bu(o[dt][4 * rr + 1] * inv);
            u.z = f2bu(o[dt][4 * rr + 2] * inv);
            u.w = f2bu(o[dt][4 * rr + 3] * inv);
            *reinterpret_cast<ushort4*>(yrow + d0) = u;
        }
    }
}

extern "C" void kernel_launch(void* const* d_in, const int* in_sizes, int n_in,
                              void* d_out, int out_size, void* d_ws, size_t ws_size,
                              hipStream_t stream) {
    const float* x      = (const float*)d_in[0];
    const float* W_attn = (const float*)d_in[1];
    const float* b_attn = (const float*)d_in[2];
    const float* W_proj = (const float*)d_in[3];
    const float* b_proj = (const float*)d_in[4];
    float* out = (float*)d_out;

    const size_t sz_x   = (size_t)M_TOT * N_EMB;
    const size_t sz_wat = (size_t)N_QKV * N_EMB;
    const size_t sz_wpt = (size_t)N_EMB * N_EMB;
    const size_t sz_hd  = (size_t)BATCH * N_HEAD * T_SEQ * HEAD_DIM;
    const size_t need = (sz_x + sz_wat + sz_wpt + 3 * sz_hd + sz_x) * sizeof(bf16);
    if (ws_size < need) return;

    bf16* xb  = (bf16*)d_ws;       // dead after QKV GEMM -> reused for V^T
    bf16* wat = xb + sz_x;
    bf16* wpt = wat + sz_wat;
    bf16* qb  = wpt + sz_wpt;
    bf16* kbf = qb + sz_hd;
    bf16* vbf = kbf + sz_hd;
    bf16* yb  = vbf + sz_hd;
    bf16* vtb = xb;                // V^T [B,H,64,T] (k-permuted)

    k_prep<<<dim3(8192), 256, 0, stream>>>(x, W_attn, W_proj, xb, wat, wpt);
    k_gemm_qkv<<<dim3(M_TOT / 128, N_QKV / 128), 256, 0, stream>>>(xb, wat, b_attn, qb, kbf, vbf);
    k_vtrans<<<dim3(T_SEQ / 64, BATCH * N_HEAD), 256, 0, stream>>>(vbf, vtb);
    k_attn<<<dim3(BATCH * N_HEAD, 64), 256, 0, stream>>>(qb, kbf, vtb, yb);
    k_gemm_proj<<<dim3(M_TOT / 64, N_EMB / 128), 256, 0, stream>>>(yb, wpt, b_proj, out);
}